// Round 5
// baseline (185.640 us; speedup 1.0000x reference)
//
#include <hip/hip_runtime.h>

// PINN jets via MFMA (bf16 3-term split, f32 accumulate), round 5:
// H/F/u0 stored in LDS PRE-SPLIT as bf16 hi/lo (producer-side
// v_cvt_pk_bf16_f32), so MFMA A-fragments are direct ds_read_b128 with no
// consumer-side conversion VALU. Layout strides chosen for <=2-way banks.
//
// Per 16-sample tile (one wave): matrix rows = 4*sample+jet (64 rows).
//   layers 2..5: Z[64x64] = H[64x64] @ Wpad[64x64]; tanh-jet mix in-lane.
//   head:        U[64x112] = H5 @ WoutPad  -> u0,u1,u3 in lane regs
//                f = -l1*u0*u1 - l2*u3 -> F[16x128] bf16 hi/lo (aliases H)
//                u0 -> packed u32 (hi<<16|lo) in H-buffer tails
//   final:       O[16x112] = F @ MdtPad[128x112];  out = u0 + O.
// mfma_f32_16x16x32_bf16: A: row=lane&15, k=(lane>>4)*8+e;
// B: col=lane&15, k=(lane>>4)*8+e; C/D: col=lane&15, row=(lane>>4)*4+reg.

typedef float  f32x4 __attribute__((ext_vector_type(4)));
typedef short  s16x8 __attribute__((ext_vector_type(8)));

constexpr int HS = 72;             // H row stride (ushorts): 144B -> 2-way
constexpr int HN = 64 * HS;        // 4608 ushorts per buffer per wave
constexpr int FS = 136;            // F row stride (ushorts): 272B -> 2-way
constexpr int U0OFF = 16 * FS;     // 2176: u0 packed-u32 region (8 rows/buf)

// ws layout (ushort units):
//   Wf   hi [L][ct4][ks2][lane][8] @ 0      (16384), lo @ 16384
//   Woutf hi [ct7][ks2][lane][8]  @ 32768   (7168),  lo @ 39936
//   Mdtf hi [ct7][ks4][lane][8]   @ 47104   (14336), lo @ 61440
constexpr int WF_LO = 16384, WO_HI = 32768, WO_LO = 39936;
constexpr int MD_HI = 47104, MD_LO = 61440;

__device__ __forceinline__ unsigned short f2b(float v) {
    unsigned int u = __builtin_bit_cast(unsigned int, v);
    unsigned int r = (u + 0x7FFFu + ((u >> 16) & 1u)) >> 16;   // RNE
    return (unsigned short)r;
}
__device__ __forceinline__ float b2f(unsigned short h) {
    return __builtin_bit_cast(float, (unsigned int)h << 16);
}
__device__ __forceinline__ unsigned int cvtpk(float lo, float hi) {
    unsigned int r;
    asm("v_cvt_pk_bf16_f32 %0, %1, %2" : "=v"(r) : "v"(lo), "v"(hi));
    return r;   // low16 = bf16(lo), high16 = bf16(hi)
}
// (v0,v1) -> hp = [b(v1)|b(v0)], lp = packed bf16 of exact residuals
__device__ __forceinline__ void cvt2(float v0, float v1,
                                     unsigned int& hp, unsigned int& lp) {
    hp = cvtpk(v0, v1);
    float r0 = v0 - __builtin_bit_cast(float, hp << 16);
    float r1 = v1 - __builtin_bit_cast(float, hp & 0xFFFF0000u);
    lp = cvtpk(r0, r1);
}
__device__ __forceinline__ f32x4 mm(s16x8 a, s16x8 b, f32x4 c) {
    return __builtin_amdgcn_mfma_f32_16x16x32_bf16(a, b, c, 0, 0, 0);
}
__device__ __forceinline__ float ftanh(float z) {
    float e = __expf(2.0f * z);
    float r = __builtin_amdgcn_rcpf(e + 1.0f);
    return fmaf(-2.0f, r, 1.0f);
}

__global__ __launch_bounds__(256) void pinn_prep(
    const float* __restrict__ alpha, const float* __restrict__ beta,
    const float* __restrict__ dtp,
    const float* __restrict__ W2, const float* __restrict__ W3,
    const float* __restrict__ W4, const float* __restrict__ W5,
    const float* __restrict__ Wout, unsigned short* __restrict__ wsu)
{
    int i = blockIdx.x * 256 + threadIdx.x;
    float v; int hi_off, lo_off;
    if (i < 16384) {                                   // hidden Ws
        int L = i >> 12, r = i & 4095;
        int ct = r >> 10, r2 = r & 1023, ks = r2 >> 9, r3 = r2 & 511;
        int lane = r3 >> 3, e = r3 & 7;
        int k = ks * 32 + (lane >> 4) * 8 + e;
        int n = ct * 16 + (lane & 15);
        const float* W = (L == 0) ? W2 : (L == 1) ? W3 : (L == 2) ? W4 : W5;
        v = (k < 50 && n < 50) ? W[k * 50 + n] : 0.0f;
        hi_off = i; lo_off = i + WF_LO;
    } else if (i < 23552) {                            // Wout
        int r = i - 16384;
        int ct = r >> 10, r2 = r & 1023, ks = r2 >> 9, r3 = r2 & 511;
        int lane = r3 >> 3, e = r3 & 7;
        int k = ks * 32 + (lane >> 4) * 8 + e;
        int col = ct * 16 + (lane & 15);
        v = (k < 50 && col < 100) ? Wout[k * 100 + col] : 0.0f;
        hi_off = WO_HI + r; lo_off = WO_LO + r;
    } else if (i < 37888) {                            // Mdt
        int r = i - 23552;
        int ct = r >> 11, r2 = r & 2047, ks = r2 >> 9, r3 = r2 & 511;
        int lane = r3 >> 3, e = r3 & 7;
        int k = ks * 32 + (lane >> 4) * 8 + e;
        int j = ct * 16 + (lane & 15);
        v = (k < 100 && j < 100) ? dtp[0] * (beta[k] - alpha[j * 100 + k]) : 0.0f;
        hi_off = MD_HI + r; lo_off = MD_LO + r;
    } else return;
    unsigned short h = f2b(v);
    wsu[hi_off] = h;
    wsu[lo_off] = f2b(v - b2f(h));
}

__global__ __launch_bounds__(128) void pinn_main(
    const float* __restrict__ X, int N,
    const float* __restrict__ W1, const float* __restrict__ b1,
    const float* __restrict__ b2, const float* __restrict__ b3,
    const float* __restrict__ b4, const float* __restrict__ b5,
    const float* __restrict__ bout,
    const float* __restrict__ l1p, const float* __restrict__ l2p,
    const unsigned short* __restrict__ wsu,
    float* __restrict__ out)
{
    __shared__ __attribute__((aligned(16))) unsigned short Hhi_all[2 * HN];
    __shared__ __attribute__((aligned(16))) unsigned short Hlo_all[2 * HN];
    int tid = threadIdx.x;
    int wv = tid >> 6, ln = tid & 63;
    int cc = ln & 15, gg = ln >> 4;
    unsigned short* Hhi = &Hhi_all[wv * HN];
    unsigned short* Hlo = &Hlo_all[wv * HN];
    int n0 = blockIdx.x * 32 + wv * 16;

    // zero both buffers (pad cols 50..63 must stay zero for all layers)
    {
        s16x8 z = {0, 0, 0, 0, 0, 0, 0, 0};
#pragma unroll
        for (int i = 0; i < 9; ++i) {
            *(s16x8*)&Hhi[(ln + 64 * i) * 8] = z;
            *(s16x8*)&Hlo[(ln + 64 * i) * 8] = z;
        }
    }

    // ---- layer 1 (width 1 -> 50), jets (x,1,0,0), pure VALU ----
    float x = (n0 + cc < N) ? X[n0 + cc] : 0.0f;
#pragma unroll
    for (int i = 0; i < 13; ++i) {
        int nn = gg + 4 * i;
        if (nn < 50) {
            float w = W1[nn], b = b1[nn];
            float z0 = fmaf(x, w, b);
            float t  = ftanh(z0);
            float s  = fmaf(-t, t, 1.0f);
            float c2 = -2.0f * t * s;
            float c3 = -2.0f * s * fmaf(3.0f, s, -2.0f);
            float w2 = w * w;
            float m0 = t, m1 = s * w, m2 = c2 * w2, m3 = c3 * w2 * w;
            unsigned int hpA, lpA, hpB, lpB;
            cvt2(m0, m1, hpA, lpA);
            cvt2(m2, m3, hpB, lpB);
            int rb = (4 * cc) * HS + nn;         // rows 4*sample + jet
            Hhi[rb]          = (unsigned short)hpA;
            Hhi[rb + HS]     = (unsigned short)(hpA >> 16);
            Hhi[rb + 2 * HS] = (unsigned short)hpB;
            Hhi[rb + 3 * HS] = (unsigned short)(hpB >> 16);
            Hlo[rb]          = (unsigned short)lpA;
            Hlo[rb + HS]     = (unsigned short)(lpA >> 16);
            Hlo[rb + 2 * HS] = (unsigned short)lpB;
            Hlo[rb + 3 * HS] = (unsigned short)(lpB >> 16);
        }
    }

    // ---- layers 2..5: MFMA + in-lane jet mix ----
#pragma unroll 1
    for (int L = 0; L < 4; ++L) {
        const float* bias = (L == 0) ? b2 : (L == 1) ? b3 : (L == 2) ? b4 : b5;
        int Lb = L * 4096;
        s16x8 ah[4][2], al[4][2];
#pragma unroll
        for (int rt = 0; rt < 4; ++rt)
#pragma unroll
            for (int ks = 0; ks < 2; ++ks) {
                int off = (16 * rt + cc) * HS + gg * 8 + 32 * ks;
                ah[rt][ks] = *(const s16x8*)&Hhi[off];
                al[rt][ks] = *(const s16x8*)&Hlo[off];
            }
#pragma unroll
        for (int ct = 0; ct < 4; ++ct) {
            int n = 16 * ct + cc;
            s16x8 bh[2], bl[2];
#pragma unroll
            for (int ks = 0; ks < 2; ++ks) {
                bh[ks] = ((const s16x8*)(wsu + Lb + (ct * 2 + ks) * 512))[ln];
                bl[ks] = ((const s16x8*)(wsu + WF_LO + Lb + (ct * 2 + ks) * 512))[ln];
            }
            f32x4 C[4];
#pragma unroll
            for (int rt = 0; rt < 4; ++rt) C[rt] = {0.f, 0.f, 0.f, 0.f};
#pragma unroll
            for (int ks = 0; ks < 2; ++ks) {
#pragma unroll
                for (int rt = 0; rt < 4; ++rt) C[rt] = mm(ah[rt][ks], bh[ks], C[rt]);
#pragma unroll
                for (int rt = 0; rt < 4; ++rt) C[rt] = mm(ah[rt][ks], bl[ks], C[rt]);
#pragma unroll
                for (int rt = 0; rt < 4; ++rt) C[rt] = mm(al[rt][ks], bh[ks], C[rt]);
            }
            if (n < 50) {
                float bval = bias[n];
#pragma unroll
                for (int rt = 0; rt < 4; ++rt) {
                    float z0 = C[rt][0] + bval, z1 = C[rt][1];
                    float z2 = C[rt][2], z3 = C[rt][3];
                    float t  = ftanh(z0);
                    float s  = fmaf(-t, t, 1.0f);
                    float c2 = -2.0f * t * s;
                    float c3 = -2.0f * s * fmaf(3.0f, s, -2.0f);
                    float z1sq = z1 * z1;
                    float m0 = t;
                    float m1 = s * z1;
                    float m2 = fmaf(c2, z1sq, s * z2);
                    float m3 = fmaf(c3, z1sq * z1, fmaf(3.0f * c2, z1 * z2, s * z3));
                    unsigned int hpA, lpA, hpB, lpB;
                    cvt2(m0, m1, hpA, lpA);
                    cvt2(m2, m3, hpB, lpB);
                    int rb = (16 * rt + 4 * gg) * HS + n;
                    Hhi[rb]          = (unsigned short)hpA;
                    Hhi[rb + HS]     = (unsigned short)(hpA >> 16);
                    Hhi[rb + 2 * HS] = (unsigned short)hpB;
                    Hhi[rb + 3 * HS] = (unsigned short)(hpB >> 16);
                    Hlo[rb]          = (unsigned short)lpA;
                    Hlo[rb + HS]     = (unsigned short)(lpA >> 16);
                    Hlo[rb + 2 * HS] = (unsigned short)lpB;
                    Hlo[rb + 3 * HS] = (unsigned short)(lpB >> 16);
                }
            }
        }
    }

    // ---- head: U = H5 @ WoutPad; write F (bf16 hi/lo) + packed u0 ----
    float l1v = l1p[0], l2v = l2p[0];
    unsigned int* u0h = (unsigned int*)(Hhi + U0OFF);
    unsigned int* u0l = (unsigned int*)(Hlo + U0OFF);
    {
        s16x8 ah[4][2], al[4][2];
#pragma unroll
        for (int rt = 0; rt < 4; ++rt)
#pragma unroll
            for (int ks = 0; ks < 2; ++ks) {
                int off = (16 * rt + cc) * HS + gg * 8 + 32 * ks;
                ah[rt][ks] = *(const s16x8*)&Hhi[off];
                al[rt][ks] = *(const s16x8*)&Hlo[off];
            }
        // zero F pad cols 112..135 (AFTER the A-frag loads; same-wave DS is
        // in-order, so the aliased H rows are read before being clobbered)
        if (ln < 48) {
            int r = ln / 3, o = ln - 3 * r;
            int off = r * FS + 112 + o * 8;
            s16x8 z = {0, 0, 0, 0, 0, 0, 0, 0};
            *(s16x8*)&Hhi[off] = z;
            *(s16x8*)&Hlo[off] = z;
        }
#pragma unroll
        for (int ct = 0; ct < 7; ++ct) {
            int col = 16 * ct + cc;
            s16x8 bh[2], bl[2];
#pragma unroll
            for (int ks = 0; ks < 2; ++ks) {
                bh[ks] = ((const s16x8*)(wsu + WO_HI + (ct * 2 + ks) * 512))[ln];
                bl[ks] = ((const s16x8*)(wsu + WO_LO + (ct * 2 + ks) * 512))[ln];
            }
            float bo = (col < 100) ? bout[col] : 0.0f;
            f32x4 C[4];
#pragma unroll
            for (int rt = 0; rt < 4; ++rt) C[rt] = {0.f, 0.f, 0.f, 0.f};
#pragma unroll
            for (int ks = 0; ks < 2; ++ks) {
#pragma unroll
                for (int rt = 0; rt < 4; ++rt) C[rt] = mm(ah[rt][ks], bh[ks], C[rt]);
#pragma unroll
                for (int rt = 0; rt < 4; ++rt) C[rt] = mm(ah[rt][ks], bl[ks], C[rt]);
#pragma unroll
                for (int rt = 0; rt < 4; ++rt) C[rt] = mm(al[rt][ks], bh[ks], C[rt]);
            }
            float u0v[4], fv[4];
#pragma unroll
            for (int rt = 0; rt < 4; ++rt) {
                u0v[rt] = C[rt][0] + bo;
                fv[rt]  = -(l1v * u0v[rt]) * C[rt][1] - l2v * C[rt][3];
            }
            // F rows 4rt+gg (sample), col: bf16 hi/lo split
            unsigned int hpA, lpA, hpB, lpB;
            cvt2(fv[0], fv[1], hpA, lpA);
            cvt2(fv[2], fv[3], hpB, lpB);
            int fb = gg * FS + col;
            Hhi[fb]           = (unsigned short)hpA;
            Hhi[fb + 4 * FS]  = (unsigned short)(hpA >> 16);
            Hhi[fb + 8 * FS]  = (unsigned short)hpB;
            Hhi[fb + 12 * FS] = (unsigned short)(hpB >> 16);
            Hlo[fb]           = (unsigned short)lpA;
            Hlo[fb + 4 * FS]  = (unsigned short)(lpA >> 16);
            Hlo[fb + 8 * FS]  = (unsigned short)lpB;
            Hlo[fb + 12 * FS] = (unsigned short)(lpB >> 16);
            // u0 packed (hi<<16|lo); rows 0..7 -> u0h, rows 8..15 -> u0l
            unsigned int hpU, lpU, hpV, lpV;
            cvt2(u0v[0], u0v[1], hpU, lpU);
            cvt2(u0v[2], u0v[3], hpV, lpV);
            u0h[gg * 112 + col]       = __builtin_amdgcn_perm(hpU, lpU, 0x05040100u);
            u0h[(4 + gg) * 112 + col] = __builtin_amdgcn_perm(hpU, lpU, 0x07060302u);
            u0l[gg * 112 + col]       = __builtin_amdgcn_perm(hpV, lpV, 0x05040100u);
            u0l[(4 + gg) * 112 + col] = __builtin_amdgcn_perm(hpV, lpV, 0x07060302u);
        }
    }

    // ---- final: O = F @ MdtPad; out = u0 + O ----
    {
        s16x8 fh[4], fl[4];
#pragma unroll
        for (int ks = 0; ks < 4; ++ks) {
            int off = cc * FS + gg * 8 + 32 * ks;     // F row = sample cc
            fh[ks] = *(const s16x8*)&Hhi[off];
            fl[ks] = *(const s16x8*)&Hlo[off];
        }
        const unsigned int* ub = (gg < 2) ? u0h : u0l;
        int rbase = (gg & 1) * 4;                      // (4gg+r) mod 8 = rbase+r
#pragma unroll
        for (int ct = 0; ct < 7; ++ct) {
            s16x8 mh[4], ml[4];
#pragma unroll
            for (int ks = 0; ks < 4; ++ks) {
                mh[ks] = ((const s16x8*)(wsu + MD_HI + (ct * 4 + ks) * 512))[ln];
                ml[ks] = ((const s16x8*)(wsu + MD_LO + (ct * 4 + ks) * 512))[ln];
            }
            f32x4 C = {0.f, 0.f, 0.f, 0.f};
#pragma unroll
            for (int ks = 0; ks < 4; ++ks) {
                C = mm(fh[ks], mh[ks], C);
                C = mm(fh[ks], ml[ks], C);
                C = mm(fl[ks], mh[ks], C);
            }
            int jcol = 16 * ct + cc;
            if (jcol < 100) {
#pragma unroll
                for (int r = 0; r < 4; ++r) {
                    unsigned int up = ub[(rbase + r) * 112 + jcol];
                    float u0 = __builtin_bit_cast(float, up & 0xFFFF0000u)
                             + __builtin_bit_cast(float, up << 16);
                    int nidx = n0 + 4 * gg + r;
                    if (nidx < N)
                        out[(size_t)nidx * 100 + jcol] = u0 + C[r];
                }
            }
        }
    }
}

extern "C" void kernel_launch(void* const* d_in, const int* in_sizes, int n_in,
                              void* d_out, int out_size, void* d_ws, size_t ws_size,
                              hipStream_t stream)
{
    const float* X     = (const float*)d_in[0];
    const float* dt    = (const float*)d_in[1];
    const float* alpha = (const float*)d_in[2];
    const float* beta  = (const float*)d_in[3];
    const float* W1    = (const float*)d_in[4];
    const float* b1    = (const float*)d_in[5];
    const float* W2    = (const float*)d_in[6];
    const float* b2    = (const float*)d_in[7];
    const float* W3    = (const float*)d_in[8];
    const float* b3    = (const float*)d_in[9];
    const float* W4    = (const float*)d_in[10];
    const float* b4    = (const float*)d_in[11];
    const float* W5    = (const float*)d_in[12];
    const float* b5    = (const float*)d_in[13];
    const float* Wout  = (const float*)d_in[14];
    const float* bout  = (const float*)d_in[15];
    const float* l1    = (const float*)d_in[16];
    const float* l2    = (const float*)d_in[17];

    unsigned short* wsu = (unsigned short*)d_ws;
    int N = in_sizes[0];

    pinn_prep<<<148, 256, 0, stream>>>(alpha, beta, dt, W2, W3, W4, W5, Wout, wsu);

    int grid = (N + 31) / 32;
    pinn_main<<<grid, 128, 0, stream>>>(X, N, W1, b1, b2, b3, b4, b5,
                                        bout, l1, l2, wsu, (float*)d_out);
}

// Round 6
// 185.329 us; speedup vs baseline: 1.0017x; 1.0017x over previous
//
#include <hip/hip_runtime.h>

// PINN jets via MFMA (bf16 3-term split, f32 accumulate), round 6:
// H stored in LDS in MFMA A-FRAGMENT ORDER [rt][ks][lane][e8] (hi/lo pre-split
// with v_cvt_pk_bf16_f32), so consumer loads are lane-linear ds_read_b128
// (conflict-free, same pattern as the weight loads). 4096 ushorts/buffer/wave
// -> 32 KB LDS/block -> 5 blocks/CU.
//
// Per 16-sample tile (one wave): matrix rows = 4*sample+jet (64 rows).
//   layers 2..5: Z[64x64] = H[64x64] @ Wpad[64x64]; tanh-jet mix in-lane.
//   head:        U[64x112] = H5 @ WoutPad -> u0,u1,u3 in lane regs
//                f -> F[16x128] bf16 hi/lo rows (aliases H region)
//                u0 -> packed u32 (hi16|lo16) in buffer tails
//   final:       O[16x112] = F @ MdtPad[128x112];  out = u0 + O.
// mfma_f32_16x16x32_bf16: A: row=lane&15, k=(lane>>4)*8+e (+32*ks);
// B: col=lane&15, k=(lane>>4)*8+e; C/D: col=lane&15, row=(lane>>4)*4+reg.
// Fragment u16 index for element (row,col n):
//   ((row>>4)*2 + (n>>5))*512 + ((n>>3)&3)*128 + (row&15)*8 + (n&7)

typedef float  f32x4 __attribute__((ext_vector_type(4)));
typedef short  s16x8 __attribute__((ext_vector_type(8)));

constexpr int HN    = 4096;        // ushorts per buffer per wave (8 FG x 512)
constexpr int FS    = 136;         // F row stride (ushorts)
constexpr int U0OFF = 16 * FS;     // 2176: u0 packed-u32 region (8 rows/buf)

// ws layout (ushort units):
//   Wf   hi [L][ct4][ks2][lane][8] @ 0      (16384), lo @ 16384
//   Woutf hi [ct7][ks2][lane][8]  @ 32768   (7168),  lo @ 39936
//   Mdtf hi [ct7][ks4][lane][8]   @ 47104   (14336), lo @ 61440
constexpr int WF_LO = 16384, WO_HI = 32768, WO_LO = 39936;
constexpr int MD_HI = 47104, MD_LO = 61440;

__device__ __forceinline__ unsigned short f2b(float v) {
    unsigned int u = __builtin_bit_cast(unsigned int, v);
    unsigned int r = (u + 0x7FFFu + ((u >> 16) & 1u)) >> 16;   // RNE
    return (unsigned short)r;
}
__device__ __forceinline__ float b2f(unsigned short h) {
    return __builtin_bit_cast(float, (unsigned int)h << 16);
}
__device__ __forceinline__ unsigned int cvtpk(float lo, float hi) {
    unsigned int r;
    asm("v_cvt_pk_bf16_f32 %0, %1, %2" : "=v"(r) : "v"(lo), "v"(hi));
    return r;   // low16 = bf16(lo), high16 = bf16(hi)
}
// (v0,v1) -> hp = [b(v1)|b(v0)], lp = packed bf16 of exact residuals
__device__ __forceinline__ void cvt2(float v0, float v1,
                                     unsigned int& hp, unsigned int& lp) {
    hp = cvtpk(v0, v1);
    float r0 = v0 - __builtin_bit_cast(float, hp << 16);
    float r1 = v1 - __builtin_bit_cast(float, hp & 0xFFFF0000u);
    lp = cvtpk(r0, r1);
}
__device__ __forceinline__ f32x4 mm(s16x8 a, s16x8 b, f32x4 c) {
    return __builtin_amdgcn_mfma_f32_16x16x32_bf16(a, b, c, 0, 0, 0);
}
__device__ __forceinline__ float ftanh(float z) {
    float e = __expf(2.0f * z);
    float r = __builtin_amdgcn_rcpf(e + 1.0f);
    return fmaf(-2.0f, r, 1.0f);
}

__global__ __launch_bounds__(256) void pinn_prep(
    const float* __restrict__ alpha, const float* __restrict__ beta,
    const float* __restrict__ dtp,
    const float* __restrict__ W2, const float* __restrict__ W3,
    const float* __restrict__ W4, const float* __restrict__ W5,
    const float* __restrict__ Wout, unsigned short* __restrict__ wsu)
{
    int i = blockIdx.x * 256 + threadIdx.x;
    float v; int hi_off, lo_off;
    if (i < 16384) {                                   // hidden Ws
        int L = i >> 12, r = i & 4095;
        int ct = r >> 10, r2 = r & 1023, ks = r2 >> 9, r3 = r2 & 511;
        int lane = r3 >> 3, e = r3 & 7;
        int k = ks * 32 + (lane >> 4) * 8 + e;
        int n = ct * 16 + (lane & 15);
        const float* W = (L == 0) ? W2 : (L == 1) ? W3 : (L == 2) ? W4 : W5;
        v = (k < 50 && n < 50) ? W[k * 50 + n] : 0.0f;
        hi_off = i; lo_off = i + WF_LO;
    } else if (i < 23552) {                            // Wout
        int r = i - 16384;
        int ct = r >> 10, r2 = r & 1023, ks = r2 >> 9, r3 = r2 & 511;
        int lane = r3 >> 3, e = r3 & 7;
        int k = ks * 32 + (lane >> 4) * 8 + e;
        int col = ct * 16 + (lane & 15);
        v = (k < 50 && col < 100) ? Wout[k * 100 + col] : 0.0f;
        hi_off = WO_HI + r; lo_off = WO_LO + r;
    } else if (i < 37888) {                            // Mdt
        int r = i - 23552;
        int ct = r >> 11, r2 = r & 2047, ks = r2 >> 9, r3 = r2 & 511;
        int lane = r3 >> 3, e = r3 & 7;
        int k = ks * 32 + (lane >> 4) * 8 + e;
        int j = ct * 16 + (lane & 15);
        v = (k < 100 && j < 100) ? dtp[0] * (beta[k] - alpha[j * 100 + k]) : 0.0f;
        hi_off = MD_HI + r; lo_off = MD_LO + r;
    } else return;
    unsigned short h = f2b(v);
    wsu[hi_off] = h;
    wsu[lo_off] = f2b(v - b2f(h));
}

__global__ __launch_bounds__(128) void pinn_main(
    const float* __restrict__ X, int N,
    const float* __restrict__ W1, const float* __restrict__ b1,
    const float* __restrict__ b2, const float* __restrict__ b3,
    const float* __restrict__ b4, const float* __restrict__ b5,
    const float* __restrict__ bout,
    const float* __restrict__ l1p, const float* __restrict__ l2p,
    const unsigned short* __restrict__ wsu,
    float* __restrict__ out)
{
    __shared__ __attribute__((aligned(16))) unsigned short Hhi_all[2 * HN];
    __shared__ __attribute__((aligned(16))) unsigned short Hlo_all[2 * HN];
    int tid = threadIdx.x;
    int wv = tid >> 6, ln = tid & 63;
    int cc = ln & 15, gg = ln >> 4;
    unsigned short* Hhi = &Hhi_all[wv * HN];
    unsigned short* Hlo = &Hlo_all[wv * HN];
    int n0 = blockIdx.x * 32 + wv * 16;

    // zero both buffers (pad cols/rows must be finite-zero)
    {
        s16x8 z = {0, 0, 0, 0, 0, 0, 0, 0};
#pragma unroll
        for (int i = 0; i < 8; ++i) {
            ((s16x8*)Hhi)[i * 64 + ln] = z;
            ((s16x8*)Hlo)[i * 64 + ln] = z;
        }
    }

    // ---- layer 1 (width 1 -> 50), jets (x,1,0,0), pure VALU ----
    // lane (cc,gg): sample cc, cols nn = gg+4i. row = 4*cc+jet.
    float x = (n0 + cc < N) ? X[n0 + cc] : 0.0f;
    int l1base = (cc >> 2) * 1024 + 32 * (cc & 3);   // rt*1024 + (row&15 base)*8
#pragma unroll
    for (int i = 0; i < 13; ++i) {
        int nn = gg + 4 * i;
        if (nn < 50) {
            float w = W1[nn], b = b1[nn];
            float z0 = fmaf(x, w, b);
            float t  = ftanh(z0);
            float s  = fmaf(-t, t, 1.0f);
            float c2 = -2.0f * t * s;
            float c3 = -2.0f * s * fmaf(3.0f, s, -2.0f);
            float w2 = w * w;
            float m0 = t, m1 = s * w, m2 = c2 * w2, m3 = c3 * w2 * w;
            unsigned int hpA, lpA, hpB, lpB;
            cvt2(m0, m1, hpA, lpA);
            cvt2(m2, m3, hpB, lpB);
            int idx = l1base + (nn >> 5) * 512 + ((nn >> 3) & 3) * 128 + (nn & 7);
            Hhi[idx]      = (unsigned short)hpA;
            Hhi[idx + 8]  = (unsigned short)(hpA >> 16);
            Hhi[idx + 16] = (unsigned short)hpB;
            Hhi[idx + 24] = (unsigned short)(hpB >> 16);
            Hlo[idx]      = (unsigned short)lpA;
            Hlo[idx + 8]  = (unsigned short)(lpA >> 16);
            Hlo[idx + 16] = (unsigned short)lpB;
            Hlo[idx + 24] = (unsigned short)(lpB >> 16);
        }
    }

    // per-ct producer write bases (layers): n = 16ct+cc fixed per ct
    int wb[4];
#pragma unroll
    for (int ct = 0; ct < 4; ++ct) {
        int n = 16 * ct + cc;
        wb[ct] = (n >> 5) * 512 + ((n >> 3) & 3) * 128 + (n & 7) + 32 * gg;
    }

    // ---- layers 2..5: MFMA + in-lane jet mix ----
#pragma unroll 1
    for (int L = 0; L < 4; ++L) {
        const float* bias = (L == 0) ? b2 : (L == 1) ? b3 : (L == 2) ? b4 : b5;
        int Lb = L * 4096;
        s16x8 ah[4][2], al[4][2];
#pragma unroll
        for (int rt = 0; rt < 4; ++rt)
#pragma unroll
            for (int ks = 0; ks < 2; ++ks) {
                int fi = (rt * 2 + ks) * 64 + ln;
                ah[rt][ks] = ((const s16x8*)Hhi)[fi];
                al[rt][ks] = ((const s16x8*)Hlo)[fi];
            }
#pragma unroll
        for (int ct = 0; ct < 4; ++ct) {
            int n = 16 * ct + cc;
            s16x8 bh[2], bl[2];
#pragma unroll
            for (int ks = 0; ks < 2; ++ks) {
                bh[ks] = ((const s16x8*)(wsu + Lb + (ct * 2 + ks) * 512))[ln];
                bl[ks] = ((const s16x8*)(wsu + WF_LO + Lb + (ct * 2 + ks) * 512))[ln];
            }
            f32x4 C[4];
#pragma unroll
            for (int rt = 0; rt < 4; ++rt) C[rt] = {0.f, 0.f, 0.f, 0.f};
#pragma unroll
            for (int ks = 0; ks < 2; ++ks) {
#pragma unroll
                for (int rt = 0; rt < 4; ++rt) C[rt] = mm(ah[rt][ks], bh[ks], C[rt]);
#pragma unroll
                for (int rt = 0; rt < 4; ++rt) C[rt] = mm(ah[rt][ks], bl[ks], C[rt]);
#pragma unroll
                for (int rt = 0; rt < 4; ++rt) C[rt] = mm(al[rt][ks], bh[ks], C[rt]);
            }
            if (n < 50) {
                float bval = bias[n];
#pragma unroll
                for (int rt = 0; rt < 4; ++rt) {
                    float z0 = C[rt][0] + bval, z1 = C[rt][1];
                    float z2 = C[rt][2], z3 = C[rt][3];
                    float t  = ftanh(z0);
                    float s  = fmaf(-t, t, 1.0f);
                    float c2 = -2.0f * t * s;
                    float c3 = -2.0f * s * fmaf(3.0f, s, -2.0f);
                    float z1sq = z1 * z1;
                    float m0 = t;
                    float m1 = s * z1;
                    float m2 = fmaf(c2, z1sq, s * z2);
                    float m3 = fmaf(c3, z1sq * z1, fmaf(3.0f * c2, z1 * z2, s * z3));
                    unsigned int hpA, lpA, hpB, lpB;
                    cvt2(m0, m1, hpA, lpA);
                    cvt2(m2, m3, hpB, lpB);
                    int idx = rt * 1024 + wb[ct];
                    Hhi[idx]      = (unsigned short)hpA;
                    Hhi[idx + 8]  = (unsigned short)(hpA >> 16);
                    Hhi[idx + 16] = (unsigned short)hpB;
                    Hhi[idx + 24] = (unsigned short)(hpB >> 16);
                    Hlo[idx]      = (unsigned short)lpA;
                    Hlo[idx + 8]  = (unsigned short)(lpA >> 16);
                    Hlo[idx + 16] = (unsigned short)lpB;
                    Hlo[idx + 24] = (unsigned short)(lpB >> 16);
                }
            }
        }
    }

    // ---- head: U = H5 @ WoutPad; write F (bf16 hi/lo rows) + packed u0 ----
    float l1v = l1p[0], l2v = l2p[0];
    unsigned int* u0h = (unsigned int*)(Hhi + U0OFF);
    unsigned int* u0l = (unsigned int*)(Hlo + U0OFF);
    {
        s16x8 ah[4][2], al[4][2];
#pragma unroll
        for (int rt = 0; rt < 4; ++rt)
#pragma unroll
            for (int ks = 0; ks < 2; ++ks) {
                int fi = (rt * 2 + ks) * 64 + ln;
                ah[rt][ks] = ((const s16x8*)Hhi)[fi];
                al[rt][ks] = ((const s16x8*)Hlo)[fi];
            }
        // zero F pad cols 112..135 (AFTER A-frag loads; same-wave DS in-order)
        if (ln < 48) {
            int r = ln / 3, o = ln - 3 * r;
            int off = r * FS + 112 + o * 8;
            s16x8 z = {0, 0, 0, 0, 0, 0, 0, 0};
            *(s16x8*)&Hhi[off] = z;
            *(s16x8*)&Hlo[off] = z;
        }
#pragma unroll
        for (int ct = 0; ct < 7; ++ct) {
            int col = 16 * ct + cc;
            s16x8 bh[2], bl[2];
#pragma unroll
            for (int ks = 0; ks < 2; ++ks) {
                bh[ks] = ((const s16x8*)(wsu + WO_HI + (ct * 2 + ks) * 512))[ln];
                bl[ks] = ((const s16x8*)(wsu + WO_LO + (ct * 2 + ks) * 512))[ln];
            }
            float bo = (col < 100) ? bout[col] : 0.0f;
            f32x4 C[4];
#pragma unroll
            for (int rt = 0; rt < 4; ++rt) C[rt] = {0.f, 0.f, 0.f, 0.f};
#pragma unroll
            for (int ks = 0; ks < 2; ++ks) {
#pragma unroll
                for (int rt = 0; rt < 4; ++rt) C[rt] = mm(ah[rt][ks], bh[ks], C[rt]);
#pragma unroll
                for (int rt = 0; rt < 4; ++rt) C[rt] = mm(ah[rt][ks], bl[ks], C[rt]);
#pragma unroll
                for (int rt = 0; rt < 4; ++rt) C[rt] = mm(al[rt][ks], bh[ks], C[rt]);
            }
            float u0v[4], fv[4];
#pragma unroll
            for (int rt = 0; rt < 4; ++rt) {
                u0v[rt] = C[rt][0] + bo;
                fv[rt]  = -(l1v * u0v[rt]) * C[rt][1] - l2v * C[rt][3];
            }
            // F rows = sample 4rt+gg, col: bf16 hi/lo split
            unsigned int hpA, lpA, hpB, lpB;
            cvt2(fv[0], fv[1], hpA, lpA);
            cvt2(fv[2], fv[3], hpB, lpB);
            int fb = gg * FS + col;
            Hhi[fb]           = (unsigned short)hpA;
            Hhi[fb + 4 * FS]  = (unsigned short)(hpA >> 16);
            Hhi[fb + 8 * FS]  = (unsigned short)hpB;
            Hhi[fb + 12 * FS] = (unsigned short)(hpB >> 16);
            Hlo[fb]           = (unsigned short)lpA;
            Hlo[fb + 4 * FS]  = (unsigned short)(lpA >> 16);
            Hlo[fb + 8 * FS]  = (unsigned short)lpB;
            Hlo[fb + 12 * FS] = (unsigned short)(lpB >> 16);
            // u0 packed (hi16|lo16); rows 0..7 -> u0h, rows 8..15 -> u0l
            unsigned int hpU, lpU, hpV, lpV;
            cvt2(u0v[0], u0v[1], hpU, lpU);
            cvt2(u0v[2], u0v[3], hpV, lpV);
            u0h[gg * 112 + col]       = __builtin_amdgcn_perm(hpU, lpU, 0x05040100u);
            u0h[(4 + gg) * 112 + col] = __builtin_amdgcn_perm(hpU, lpU, 0x07060302u);
            u0l[gg * 112 + col]       = __builtin_amdgcn_perm(hpV, lpV, 0x05040100u);
            u0l[(4 + gg) * 112 + col] = __builtin_amdgcn_perm(hpV, lpV, 0x07060302u);
        }
    }

    // ---- final: O = F @ MdtPad; out = u0 + O ----
    {
        s16x8 fh[4], fl[4];
#pragma unroll
        for (int ks = 0; ks < 4; ++ks) {
            int off = cc * FS + gg * 8 + 32 * ks;     // F row = sample cc
            fh[ks] = *(const s16x8*)&Hhi[off];
            fl[ks] = *(const s16x8*)&Hlo[off];
        }
        const unsigned int* ub = (gg < 2) ? u0h : u0l;
        int rbase = (gg & 1) * 4;                      // (4gg+r) mod 8 = rbase+r
#pragma unroll
        for (int ct = 0; ct < 7; ++ct) {
            s16x8 mh[4], ml[4];
#pragma unroll
            for (int ks = 0; ks < 4; ++ks) {
                mh[ks] = ((const s16x8*)(wsu + MD_HI + (ct * 4 + ks) * 512))[ln];
                ml[ks] = ((const s16x8*)(wsu + MD_LO + (ct * 4 + ks) * 512))[ln];
            }
            f32x4 C = {0.f, 0.f, 0.f, 0.f};
#pragma unroll
            for (int ks = 0; ks < 4; ++ks) {
                C = mm(fh[ks], mh[ks], C);
                C = mm(fh[ks], ml[ks], C);
                C = mm(fl[ks], mh[ks], C);
            }
            int jcol = 16 * ct + cc;
            if (jcol < 100) {
#pragma unroll
                for (int r = 0; r < 4; ++r) {
                    unsigned int up = ub[(rbase + r) * 112 + jcol];
                    float u0 = __builtin_bit_cast(float, up & 0xFFFF0000u)
                             + __builtin_bit_cast(float, up << 16);
                    int nidx = n0 + 4 * gg + r;
                    if (nidx < N)
                        out[(size_t)nidx * 100 + jcol] = u0 + C[r];
                }
            }
        }
    }
}

extern "C" void kernel_launch(void* const* d_in, const int* in_sizes, int n_in,
                              void* d_out, int out_size, void* d_ws, size_t ws_size,
                              hipStream_t stream)
{
    const float* X     = (const float*)d_in[0];
    const float* dt    = (const float*)d_in[1];
    const float* alpha = (const float*)d_in[2];
    const float* beta  = (const float*)d_in[3];
    const float* W1    = (const float*)d_in[4];
    const float* b1    = (const float*)d_in[5];
    const float* W2    = (const float*)d_in[6];
    const float* b2    = (const float*)d_in[7];
    const float* W3    = (const float*)d_in[8];
    const float* b3    = (const float*)d_in[9];
    const float* W4    = (const float*)d_in[10];
    const float* b4    = (const float*)d_in[11];
    const float* W5    = (const float*)d_in[12];
    const float* b5    = (const float*)d_in[13];
    const float* Wout  = (const float*)d_in[14];
    const float* bout  = (const float*)d_in[15];
    const float* l1    = (const float*)d_in[16];
    const float* l2    = (const float*)d_in[17];

    unsigned short* wsu = (unsigned short*)d_ws;
    int N = in_sizes[0];

    pinn_prep<<<148, 256, 0, stream>>>(alpha, beta, dt, W2, W3, W4, W5, Wout, wsu);

    int grid = (N + 31) / 32;
    pinn_main<<<grid, 128, 0, stream>>>(X, N, W1, b1, b2, b3, b4, b5,
                                        bout, l1, l2, wsu, (float*)d_out);
}

// Round 8
// 162.919 us; speedup vs baseline: 1.1395x; 1.1376x over previous
//
#include <hip/hip_runtime.h>

// PINN jets via MFMA, round 8: TRANSPOSED network — zero cross-lane movement.
//
// Identity: mfma_f32_16x16x16 C/D layout (col=lane&15, row=4*(lane>>4)+reg)
// == its B-fragment layout (col=lane&15, k=4*(lane>>4)+e). Keeping every
// activation matrix TRANSPOSED (G = H^T) and computing Z'^T = W'^T @ H'^T
// (activations as B-operand) makes each layer's output directly consumable
// by the next layer: MFMA -> in-lane jet mix -> cvt_pk -> next MFMA.
//
// One wave = 16 samples. G cols s' = 16*jet + sample (so all 4 jets of a
// (neuron, sample) sit in one lane across the 4 jet-tiles -> in-lane mixing).
// G rows = neurons (50 + pad to 64), as 4 row-tiles (krt).
//   layers 2..5: G' = mix( W_L^T(A-frags) @ G(B-frags) )       192 MFMA each
//   head:        U^T = Wout^T @ G5 for jets {0,1,3}            252 MFMA
//                u0 -> LDS stage; f = -l1*u0*u1 - l2*u3 (in-lane) -> F frags
//   final:       out^T = u0^T + Mdt^T @ F^T                    147 MFMA
// Weights pre-transposed/padded/split (bf16 hi/lo, 3-term split AhBh+AhBl+AlBh)
// into A-fragment order by pinn_prep. LDS: only a 16x116 f32 output stage.

typedef float f32x4 __attribute__((ext_vector_type(4)));
typedef short s16x4 __attribute__((ext_vector_type(4)));

// ws layout (ushort units):
//   WhidT hi [l4][jrt4][krt4][lane64][e4] @ 0     (16384), lo @ 16384
//   WoutT hi [jrt7][krt4][lane][e4]      @ 32768  (7168),  lo @ 39936
//   MdtT  hi [jrt7][krt7][lane][e4]      @ 47104  (12544), lo @ 59648
constexpr int WH_LO = 16384, WO_HI = 32768, WO_LO = 39936;
constexpr int MD_HI = 47104, MD_LO = 59648;

__device__ __forceinline__ unsigned short f2b(float v) {
    unsigned int u = __builtin_bit_cast(unsigned int, v);
    unsigned int r = (u + 0x7FFFu + ((u >> 16) & 1u)) >> 16;   // RNE
    return (unsigned short)r;
}
__device__ __forceinline__ float b2f(unsigned short h) {
    return __builtin_bit_cast(float, (unsigned int)h << 16);
}
__device__ __forceinline__ unsigned int cvtpk(float lo, float hi) {
    unsigned int r;
    asm("v_cvt_pk_bf16_f32 %0, %1, %2" : "=v"(r) : "v"(lo), "v"(hi));
    return r;   // low16 = bf16(lo), high16 = bf16(hi)
}
__device__ __forceinline__ void cvt2(float v0, float v1,
                                     unsigned int& hp, unsigned int& lp) {
    hp = cvtpk(v0, v1);
    float r0 = v0 - __builtin_bit_cast(float, hp << 16);
    float r1 = v1 - __builtin_bit_cast(float, hp & 0xFFFF0000u);
    lp = cvtpk(r0, r1);
}
__device__ __forceinline__ s16x4 mkfrag(unsigned int a, unsigned int b) {
    union { unsigned int u[2]; s16x4 v; } x;
    x.u[0] = a; x.u[1] = b;
    return x.v;
}
__device__ __forceinline__ f32x4 mm16(s16x4 a, s16x4 b, f32x4 c) {
    return __builtin_amdgcn_mfma_f32_16x16x16bf16_1k(a, b, c, 0, 0, 0);
}
__device__ __forceinline__ float ftanh(float z) {
    float e = __expf(2.0f * z);
    float r = __builtin_amdgcn_rcpf(e + 1.0f);
    return fmaf(-2.0f, r, 1.0f);
}

__global__ __launch_bounds__(256) void pinn_prep(
    const float* __restrict__ alpha, const float* __restrict__ beta,
    const float* __restrict__ dtp,
    const float* __restrict__ W2, const float* __restrict__ W3,
    const float* __restrict__ W4, const float* __restrict__ W5,
    const float* __restrict__ Wout, unsigned short* __restrict__ wsu)
{
    int i = blockIdx.x * 256 + threadIdx.x;
    float v; int hi_off, lo_off;
    if (i < 16384) {                                   // hidden W^T A-frags
        int l = i >> 12, r = i & 4095;
        int t = r >> 8, jrt = t >> 2, krt = t & 3;
        int lane = (r >> 2) & 63, e = r & 3;
        int cc = lane & 15, gg = lane >> 4;
        int j = 16 * jrt + cc, n = 16 * krt + 4 * gg + e;
        const float* W = (l == 0) ? W2 : (l == 1) ? W3 : (l == 2) ? W4 : W5;
        v = (n < 50 && j < 50) ? W[n * 50 + j] : 0.0f;
        hi_off = i; lo_off = i + WH_LO;
    } else if (i < 23552) {                            // Wout^T A-frags
        int r = i - 16384;
        int t = r >> 8, jrt = t >> 2, krt = t & 3;
        int lane = (r >> 2) & 63, e = r & 3;
        int cc = lane & 15, gg = lane >> 4;
        int j = 16 * jrt + cc, n = 16 * krt + 4 * gg + e;
        v = (n < 50 && j < 100) ? Wout[n * 100 + j] : 0.0f;
        hi_off = WO_HI + r; lo_off = WO_LO + r;
    } else if (i < 36096) {                            // Mdt^T A-frags
        int r = i - 23552;
        int t = r >> 8, jrt = t / 7, krt = t % 7;
        int lane = (r >> 2) & 63, e = r & 3;
        int cc = lane & 15, gg = lane >> 4;
        int j = 16 * jrt + cc, k = 16 * krt + 4 * gg + e;
        v = (j < 100 && k < 100) ? dtp[0] * (beta[k] - alpha[j * 100 + k]) : 0.0f;
        hi_off = MD_HI + r; lo_off = MD_LO + r;
    } else return;
    unsigned short h = f2b(v);
    wsu[hi_off] = h;
    wsu[lo_off] = f2b(v - b2f(h));
}

// One hidden layer: G(in frags) -> mix -> G(out frags). All in registers.
__device__ __forceinline__ void hidden_layer(
    const unsigned short* __restrict__ wsu, int Lb,
    const float* __restrict__ bias, int ln, int gg,
    const s16x4 (&gh)[4][4], const s16x4 (&gl)[4][4],
    s16x4 (&nh)[4][4], s16x4 (&nl)[4][4])
{
#pragma unroll
    for (int jrt = 0; jrt < 4; ++jrt) {
        f32x4 acc[4];
#pragma unroll
        for (int ct = 0; ct < 4; ++ct) acc[ct] = (f32x4){0.f, 0.f, 0.f, 0.f};
#pragma unroll
        for (int krt = 0; krt < 4; ++krt) {
            s16x4 wh = *(const s16x4*)(wsu + Lb + (jrt * 4 + krt) * 256 + ln * 4);
            s16x4 wl = *(const s16x4*)(wsu + WH_LO + Lb + (jrt * 4 + krt) * 256 + ln * 4);
#pragma unroll
            for (int ct = 0; ct < 4; ++ct) {
                acc[ct] = mm16(wh, gh[krt][ct], acc[ct]);
                acc[ct] = mm16(wh, gl[krt][ct], acc[ct]);
                acc[ct] = mm16(wl, gh[krt][ct], acc[ct]);
            }
        }
        float bv[4];
        if (jrt < 3) {
            float4 b4 = *(const float4*)(bias + 16 * jrt + 4 * gg);
            bv[0] = b4.x; bv[1] = b4.y; bv[2] = b4.z; bv[3] = b4.w;
        } else {
#pragma unroll
            for (int r = 0; r < 4; ++r) {
                int j = 48 + 4 * gg + r;
                bv[r] = (j < 50) ? bias[j] : 0.0f;
            }
        }
        float m[4][4];
#pragma unroll
        for (int r = 0; r < 4; ++r) {
            float z0 = acc[0][r] + bv[r], z1 = acc[1][r];
            float z2 = acc[2][r], z3 = acc[3][r];
            float t  = ftanh(z0);
            float sd = fmaf(-t, t, 1.0f);
            float c2 = -2.0f * t * sd;
            float c3 = -2.0f * sd * fmaf(3.0f, sd, -2.0f);
            float z1sq = z1 * z1;
            m[0][r] = t;
            m[1][r] = sd * z1;
            m[2][r] = fmaf(c2, z1sq, sd * z2);
            m[3][r] = fmaf(c3, z1sq * z1, fmaf(3.0f * c2, z1 * z2, sd * z3));
        }
#pragma unroll
        for (int ct = 0; ct < 4; ++ct) {
            unsigned int hp0, lp0, hp1, lp1;
            cvt2(m[ct][0], m[ct][1], hp0, lp0);
            cvt2(m[ct][2], m[ct][3], hp1, lp1);
            nh[jrt][ct] = mkfrag(hp0, hp1);
            nl[jrt][ct] = mkfrag(lp0, lp1);
        }
    }
}

__global__ __launch_bounds__(64, 3) void pinn_main(
    const float* __restrict__ X, int N,
    const float* __restrict__ W1, const float* __restrict__ b1,
    const float* __restrict__ b2, const float* __restrict__ b3,
    const float* __restrict__ b4, const float* __restrict__ b5,
    const float* __restrict__ bout,
    const float* __restrict__ l1p, const float* __restrict__ l2p,
    const unsigned short* __restrict__ wsu,
    float* __restrict__ out)
{
    __shared__ __align__(16) float sout[16 * 116];
    const int ln = threadIdx.x;
    const int cc = ln & 15, gg = ln >> 4;
    const int n0 = blockIdx.x * 16;

    s16x4 gAh[4][4], gAl[4][4], gBh[4][4], gBl[4][4];

    // ---- layer 1: width 1 -> 50, jets (x,1,0,0), in-lane ----
    float x = (n0 + cc < N) ? X[n0 + cc] : 0.0f;
#pragma unroll
    for (int rt = 0; rt < 4; ++rt) {
        float wv[4], bv[4];
        if (rt < 3) {
            float4 w4 = *(const float4*)(W1 + 16 * rt + 4 * gg);
            float4 b4 = *(const float4*)(b1 + 16 * rt + 4 * gg);
            wv[0] = w4.x; wv[1] = w4.y; wv[2] = w4.z; wv[3] = w4.w;
            bv[0] = b4.x; bv[1] = b4.y; bv[2] = b4.z; bv[3] = b4.w;
        } else {
#pragma unroll
            for (int r = 0; r < 4; ++r) {
                int n = 48 + 4 * gg + r;
                wv[r] = (n < 50) ? W1[n] : 0.0f;
                bv[r] = (n < 50) ? b1[n] : 0.0f;
            }
        }
        float m[4][4];
#pragma unroll
        for (int r = 0; r < 4; ++r) {
            float w  = wv[r];
            float z0 = fmaf(x, w, bv[r]);
            float t  = ftanh(z0);
            float sd = fmaf(-t, t, 1.0f);
            float c2 = -2.0f * t * sd;
            float c3 = -2.0f * sd * fmaf(3.0f, sd, -2.0f);
            float w2 = w * w;
            m[0][r] = t; m[1][r] = sd * w; m[2][r] = c2 * w2; m[3][r] = c3 * w2 * w;
        }
#pragma unroll
        for (int ct = 0; ct < 4; ++ct) {
            unsigned int hp0, lp0, hp1, lp1;
            cvt2(m[ct][0], m[ct][1], hp0, lp0);
            cvt2(m[ct][2], m[ct][3], hp1, lp1);
            gAh[rt][ct] = mkfrag(hp0, hp1);
            gAl[rt][ct] = mkfrag(lp0, lp1);
        }
    }

    // ---- layers 2..5 (A->B->A->B->A) ----
#pragma unroll 1
    for (int L = 0; L < 2; ++L) {
        const float* biasA = (L == 0) ? b2 : b4;
        const float* biasB = (L == 0) ? b3 : b5;
        hidden_layer(wsu, (2 * L) * 4096,     biasA, ln, gg, gAh, gAl, gBh, gBl);
        hidden_layer(wsu, (2 * L + 1) * 4096, biasB, ln, gg, gBh, gBl, gAh, gAl);
    }

    // ---- head: U^T = Wout^T @ G5 (jets 0,1,3); u0 -> LDS, f -> frags ----
    const float l1v = l1p[0], l2v = l2p[0];
    s16x4 fh[7], fl[7];
#pragma unroll
    for (int jrt = 0; jrt < 7; ++jrt) {
        f32x4 a0 = {0.f, 0.f, 0.f, 0.f};
        f32x4 a1 = {0.f, 0.f, 0.f, 0.f};
        f32x4 a3 = {0.f, 0.f, 0.f, 0.f};
#pragma unroll
        for (int krt = 0; krt < 4; ++krt) {
            s16x4 wh = *(const s16x4*)(wsu + WO_HI + (jrt * 4 + krt) * 256 + ln * 4);
            s16x4 wl = *(const s16x4*)(wsu + WO_LO + (jrt * 4 + krt) * 256 + ln * 4);
            a0 = mm16(wh, gAh[krt][0], a0);
            a0 = mm16(wh, gAl[krt][0], a0);
            a0 = mm16(wl, gAh[krt][0], a0);
            a1 = mm16(wh, gAh[krt][1], a1);
            a1 = mm16(wh, gAl[krt][1], a1);
            a1 = mm16(wl, gAh[krt][1], a1);
            a3 = mm16(wh, gAh[krt][3], a3);
            a3 = mm16(wh, gAl[krt][3], a3);
            a3 = mm16(wl, gAh[krt][3], a3);
        }
        float bo[4];
        if (jrt < 6) {
            float4 b4 = *(const float4*)(bout + 16 * jrt + 4 * gg);
            bo[0] = b4.x; bo[1] = b4.y; bo[2] = b4.z; bo[3] = b4.w;
        } else {
#pragma unroll
            for (int r = 0; r < 4; ++r) {
                int j = 96 + 4 * gg + r;
                bo[r] = (j < 100) ? bout[j] : 0.0f;
            }
        }
        float u0[4], fv[4];
#pragma unroll
        for (int r = 0; r < 4; ++r) {
            u0[r] = a0[r] + bo[r];
            fv[r] = -(l1v * u0[r]) * a1[r] - l2v * a3[r];   // dt folded in MdtT
        }
        *(float4*)&sout[cc * 116 + 16 * jrt + 4 * gg] =
            make_float4(u0[0], u0[1], u0[2], u0[3]);        // stage u0
        unsigned int hp0, lp0, hp1, lp1;
        cvt2(fv[0], fv[1], hp0, lp0);
        cvt2(fv[2], fv[3], hp1, lp1);
        fh[jrt] = mkfrag(hp0, hp1);
        fl[jrt] = mkfrag(lp0, lp1);
    }

    // ---- final: out^T = u0^T + Mdt^T @ F^T ----
#pragma unroll
    for (int jrt = 0; jrt < 7; ++jrt) {
        f32x4 acc = {0.f, 0.f, 0.f, 0.f};
#pragma unroll
        for (int krt = 0; krt < 7; ++krt) {
            s16x4 mh = *(const s16x4*)(wsu + MD_HI + (jrt * 7 + krt) * 256 + ln * 4);
            s16x4 ml = *(const s16x4*)(wsu + MD_LO + (jrt * 7 + krt) * 256 + ln * 4);
            acc = mm16(mh, fh[krt], acc);
            acc = mm16(mh, fl[krt], acc);
            acc = mm16(ml, fh[krt], acc);
        }
        float* sp = &sout[cc * 116 + 16 * jrt + 4 * gg];
        float4 u0v = *(const float4*)sp;                    // same-lane readback
        *(float4*)sp = make_float4(u0v.x + acc[0], u0v.y + acc[1],
                                   u0v.z + acc[2], u0v.w + acc[3]);
    }
    __syncthreads();

    // ---- coalesced store: lane = (sample s, quarter q) ----
    {
        int s = ln >> 2, q = ln & 3;
        int nidx = n0 + s;
        if (nidx < N) {
            float* op = out + (size_t)nidx * 100;
#pragma unroll
            for (int i2 = 0; i2 < 7; ++i2) {
                int j = 28 * q + 4 * i2;
                if (j < 100) {
                    float4 v = *(const float4*)&sout[s * 116 + j];
                    *(float4*)(op + j) = v;
                }
            }
        }
    }
}

extern "C" void kernel_launch(void* const* d_in, const int* in_sizes, int n_in,
                              void* d_out, int out_size, void* d_ws, size_t ws_size,
                              hipStream_t stream)
{
    const float* X     = (const float*)d_in[0];
    const float* dt    = (const float*)d_in[1];
    const float* alpha = (const float*)d_in[2];
    const float* beta  = (const float*)d_in[3];
    const float* W1    = (const float*)d_in[4];
    const float* b1    = (const float*)d_in[5];
    const float* W2    = (const float*)d_in[6];
    const float* b2    = (const float*)d_in[7];
    const float* W3    = (const float*)d_in[8];
    const float* b3    = (const float*)d_in[9];
    const float* W4    = (const float*)d_in[10];
    const float* b4    = (const float*)d_in[11];
    const float* W5    = (const float*)d_in[12];
    const float* b5    = (const float*)d_in[13];
    const float* Wout  = (const float*)d_in[14];
    const float* bout  = (const float*)d_in[15];
    const float* l1    = (const float*)d_in[16];
    const float* l2    = (const float*)d_in[17];

    unsigned short* wsu = (unsigned short*)d_ws;
    int N = in_sizes[0];

    pinn_prep<<<141, 256, 0, stream>>>(alpha, beta, dt, W2, W3, W4, W5, Wout, wsu);

    int grid = (N + 15) / 16;
    pinn_main<<<grid, 64, 0, stream>>>(X, N, W1, b1, b2, b3, b4, b5,
                                       bout, l1, l2, wsu, (float*)d_out);
}

// Round 10
// 150.861 us; speedup vs baseline: 1.2305x; 1.0799x over previous
//
#include <hip/hip_runtime.h>

// PINN jets via MFMA, round 10: transposed network (zero cross-lane) on the
// fast K=32 op (mfma_f32_16x16x32_bf16) via slot-permuted K.
//
// Slot map (both operands must agree; MFMA reduces over slots s = 8*gg+e):
//   neuron(krt, s) = 32*krt + 16*(e>>2) + 4*gg + (e&3)
// chosen so C/D output (col=lane&15, row=4*gg+reg, tiles jrt) packs straight
// into next-layer B-frags IN-LANE: value for jrt=2*kd+p, reg q goes to
// u32 slot 2p+(q>>1) of frag[kd] (cvt_pk pairs). Weights (W^T, Wout^T, Mdt^T)
// pre-permuted into matching A-frag order by pinn_prep.
//
// r9 NaN fix: ALL fragment vectors are zero-initialized before any partial
// element write (no undef insertelement -> no poison through bit_cast/MFMA).
// Also: 3-term split accumulated in TWO independent chains (accA = AhBh,
// accB = AhBl + AlBh) to halve MFMA dependency-chain length.
//
// One wave = 16 samples; G cols = samples, 4 jets as 4 separate B-frags.
//   layers 2..5: 4 jrt x 2 krt x 4 jets x 3 = 96 MFMA each
//   head (jets 0,1,3): 7 x 2 x 9 = 126; f,u0 in-lane; u0 staged in LDS
//   final (K=128 pad): 7 x 4 x 3 = 84 MFMA;  out = u0 + Mdt^T @ F^T
// LDS: per-wave 16x116 f32 output stage only.

typedef float f32x4 __attribute__((ext_vector_type(4)));
typedef short s16x8 __attribute__((ext_vector_type(8)));
typedef unsigned int u32x4 __attribute__((ext_vector_type(4)));

// ws layout (ushort units):
//   WhidT hi [l4][jrt4][krt2][lane64][e8] @ 0     (16384), lo @ 16384
//   WoutT hi [jrt7][krt2][lane][e8]      @ 32768  (7168),  lo @ 39936
//   MdtT  hi [jrt7][kt4][lane][e8]       @ 47104  (14336), lo @ 61440
constexpr int WH_LO = 16384, WO_HI = 32768, WO_LO = 39936;
constexpr int MD_HI = 47104, MD_LO = 61440;

__device__ __forceinline__ unsigned short f2b(float v) {
    unsigned int u = __builtin_bit_cast(unsigned int, v);
    unsigned int r = (u + 0x7FFFu + ((u >> 16) & 1u)) >> 16;   // RNE
    return (unsigned short)r;
}
__device__ __forceinline__ float b2f(unsigned short h) {
    return __builtin_bit_cast(float, (unsigned int)h << 16);
}
__device__ __forceinline__ unsigned int cvtpk(float lo, float hi) {
    unsigned int r;
    asm("v_cvt_pk_bf16_f32 %0, %1, %2" : "=v"(r) : "v"(lo), "v"(hi));
    return r;   // low16 = bf16(lo), high16 = bf16(hi)
}
__device__ __forceinline__ void cvt2(float v0, float v1,
                                     unsigned int& hp, unsigned int& lp) {
    hp = cvtpk(v0, v1);
    float r0 = v0 - __builtin_bit_cast(float, hp << 16);
    float r1 = v1 - __builtin_bit_cast(float, hp & 0xFFFF0000u);
    lp = cvtpk(r0, r1);
}
__device__ __forceinline__ s16x8 asfrag(u32x4 u) {
    return __builtin_bit_cast(s16x8, u);
}
__device__ __forceinline__ f32x4 mm(s16x8 a, s16x8 b, f32x4 c) {
    return __builtin_amdgcn_mfma_f32_16x16x32_bf16(a, b, c, 0, 0, 0);
}
__device__ __forceinline__ float ftanh(float z) {
    float e = __expf(2.0f * z);
    float r = __builtin_amdgcn_rcpf(e + 1.0f);
    return fmaf(-2.0f, r, 1.0f);
}

__global__ __launch_bounds__(256) void pinn_prep(
    const float* __restrict__ alpha, const float* __restrict__ beta,
    const float* __restrict__ dtp,
    const float* __restrict__ W2, const float* __restrict__ W3,
    const float* __restrict__ W4, const float* __restrict__ W5,
    const float* __restrict__ Wout, unsigned short* __restrict__ wsu)
{
    int i = blockIdx.x * 256 + threadIdx.x;
    float v; int hi_off, lo_off;
    if (i < 16384) {                                   // hidden W^T A-frags
        int l = i >> 12, r = i & 4095;
        int t = r >> 9, jrt = t >> 1, krt = t & 1;
        int lane = (r >> 3) & 63, e = r & 7;
        int gg = lane >> 4;
        int j = 16 * jrt + (lane & 15);
        int n = 32 * krt + 16 * (e >> 2) + 4 * gg + (e & 3);
        const float* W = (l == 0) ? W2 : (l == 1) ? W3 : (l == 2) ? W4 : W5;
        v = (n < 50 && j < 50) ? W[n * 50 + j] : 0.0f;
        hi_off = i; lo_off = i + WH_LO;
    } else if (i < 23552) {                            // Wout^T A-frags
        int r = i - 16384;
        int t = r >> 9, jrt = t >> 1, krt = t & 1;
        int lane = (r >> 3) & 63, e = r & 7;
        int gg = lane >> 4;
        int j = 16 * jrt + (lane & 15);
        int n = 32 * krt + 16 * (e >> 2) + 4 * gg + (e & 3);
        v = (n < 50 && j < 100) ? Wout[n * 100 + j] : 0.0f;
        hi_off = WO_HI + r; lo_off = WO_LO + r;
    } else if (i < 37888) {                            // Mdt^T A-frags
        int r = i - 23552;
        int t = r >> 9, jrt = t >> 2, kt = t & 3;
        int lane = (r >> 3) & 63, e = r & 7;
        int gg = lane >> 4;
        int j = 16 * jrt + (lane & 15);
        int k = 32 * kt + 16 * (e >> 2) + 4 * gg + (e & 3);
        v = (j < 100 && k < 100) ? dtp[0] * (beta[k] - alpha[j * 100 + k]) : 0.0f;
        hi_off = MD_HI + r; lo_off = MD_LO + r;
    } else return;
    unsigned short h = f2b(v);
    wsu[hi_off] = h;
    wsu[lo_off] = f2b(v - b2f(h));
}

// One hidden layer: G(in B-frags) -> MFMA -> mix -> G(out B-frags). Registers.
__device__ __forceinline__ void hidden_layer(
    const unsigned short* __restrict__ wsu, int Lb,
    const float* __restrict__ bias, int ln, int gg,
    const u32x4 (&gh)[2][4], const u32x4 (&gl)[2][4],
    u32x4 (&nh)[2][4], u32x4 (&nl)[2][4])
{
#pragma unroll
    for (int kd = 0; kd < 2; ++kd)
#pragma unroll
        for (int ct = 0; ct < 4; ++ct) {
            nh[kd][ct] = (u32x4){0u, 0u, 0u, 0u};
            nl[kd][ct] = (u32x4){0u, 0u, 0u, 0u};
        }
#pragma unroll
    for (int jrt = 0; jrt < 4; ++jrt) {
        f32x4 accA[4], accB[4];
#pragma unroll
        for (int ct = 0; ct < 4; ++ct) {
            accA[ct] = (f32x4){0.f, 0.f, 0.f, 0.f};
            accB[ct] = (f32x4){0.f, 0.f, 0.f, 0.f};
        }
#pragma unroll
        for (int krt = 0; krt < 2; ++krt) {
            s16x8 wh = *(const s16x8*)(wsu + Lb + (jrt * 2 + krt) * 512 + ln * 8);
            s16x8 wl = *(const s16x8*)(wsu + WH_LO + Lb + (jrt * 2 + krt) * 512 + ln * 8);
#pragma unroll
            for (int ct = 0; ct < 4; ++ct) {
                s16x8 bh = asfrag(gh[krt][ct]);
                s16x8 bl = asfrag(gl[krt][ct]);
                accA[ct] = mm(wh, bh, accA[ct]);
                accB[ct] = mm(wh, bl, accB[ct]);
                accB[ct] = mm(wl, bh, accB[ct]);
            }
        }
        float bv[4];
        if (jrt < 3) {
            float4 b4 = *(const float4*)(bias + 16 * jrt + 4 * gg);
            bv[0] = b4.x; bv[1] = b4.y; bv[2] = b4.z; bv[3] = b4.w;
        } else {
#pragma unroll
            for (int r = 0; r < 4; ++r) {
                int j = 48 + 4 * gg + r;
                bv[r] = (j < 50) ? bias[j] : 0.0f;
            }
        }
        float m[4][4];
#pragma unroll
        for (int r = 0; r < 4; ++r) {
            float z0 = accA[0][r] + accB[0][r] + bv[r];
            float z1 = accA[1][r] + accB[1][r];
            float z2 = accA[2][r] + accB[2][r];
            float z3 = accA[3][r] + accB[3][r];
            float t  = ftanh(z0);
            float sd = fmaf(-t, t, 1.0f);
            float c2 = -2.0f * t * sd;
            float c3 = -2.0f * sd * fmaf(3.0f, sd, -2.0f);
            float z1sq = z1 * z1;
            m[0][r] = t;
            m[1][r] = sd * z1;
            m[2][r] = fmaf(c2, z1sq, sd * z2);
            m[3][r] = fmaf(c3, z1sq * z1, fmaf(3.0f * c2, z1 * z2, sd * z3));
        }
        const int kd = jrt >> 1, p = jrt & 1;
#pragma unroll
        for (int ct = 0; ct < 4; ++ct) {
            unsigned int hp0, lp0, hp1, lp1;
            cvt2(m[ct][0], m[ct][1], hp0, lp0);
            cvt2(m[ct][2], m[ct][3], hp1, lp1);
            nh[kd][ct][2 * p]     = hp0;
            nh[kd][ct][2 * p + 1] = hp1;
            nl[kd][ct][2 * p]     = lp0;
            nl[kd][ct][2 * p + 1] = lp1;
        }
    }
}

__global__ __launch_bounds__(128, 2) void pinn_main(
    const float* __restrict__ X, int N,
    const float* __restrict__ W1, const float* __restrict__ b1,
    const float* __restrict__ b2, const float* __restrict__ b3,
    const float* __restrict__ b4, const float* __restrict__ b5,
    const float* __restrict__ bout,
    const float* __restrict__ l1p, const float* __restrict__ l2p,
    const unsigned short* __restrict__ wsu,
    float* __restrict__ out)
{
    __shared__ __align__(16) float soutA[2][16 * 116];
    const int tid = threadIdx.x;
    const int wv = tid >> 6, ln = tid & 63;
    const int cc = ln & 15, gg = ln >> 4;
    const int n0 = blockIdx.x * 32 + wv * 16;
    float* so = soutA[wv];

    u32x4 gAh[2][4], gAl[2][4], gBh[2][4], gBl[2][4];
#pragma unroll
    for (int krt = 0; krt < 2; ++krt)
#pragma unroll
        for (int ct = 0; ct < 4; ++ct) {
            gAh[krt][ct] = (u32x4){0u, 0u, 0u, 0u};
            gAl[krt][ct] = (u32x4){0u, 0u, 0u, 0u};
        }

    // ---- layer 1: width 1 -> 50, jets (x,1,0,0), in-lane packing ----
    float x = (n0 + cc < N) ? X[n0 + cc] : 0.0f;
#pragma unroll
    for (int krt = 0; krt < 2; ++krt)
#pragma unroll
        for (int jf = 0; jf < 2; ++jf) {
            float m[4][4];
#pragma unroll
            for (int q = 0; q < 4; ++q) {
                int n = 32 * krt + 16 * jf + 4 * gg + q;
                float w = (n < 50) ? W1[n] : 0.0f;
                float b = (n < 50) ? b1[n] : 0.0f;
                float z0 = fmaf(x, w, b);
                float t  = ftanh(z0);
                float sd = fmaf(-t, t, 1.0f);
                float c2 = -2.0f * t * sd;
                float c3 = -2.0f * sd * fmaf(3.0f, sd, -2.0f);
                float w2 = w * w;
                m[0][q] = t; m[1][q] = sd * w; m[2][q] = c2 * w2; m[3][q] = c3 * w2 * w;
            }
#pragma unroll
            for (int ct = 0; ct < 4; ++ct) {
                unsigned int hp0, lp0, hp1, lp1;
                cvt2(m[ct][0], m[ct][1], hp0, lp0);
                cvt2(m[ct][2], m[ct][3], hp1, lp1);
                gAh[krt][ct][2 * jf]     = hp0;
                gAh[krt][ct][2 * jf + 1] = hp1;
                gAl[krt][ct][2 * jf]     = lp0;
                gAl[krt][ct][2 * jf + 1] = lp1;
            }
        }

    // ---- layers 2..5 (A->B->A->B->A) ----
#pragma unroll 1
    for (int L = 0; L < 2; ++L) {
        hidden_layer(wsu, (2 * L) * 4096,     (L == 0) ? b2 : b4, ln, gg,
                     gAh, gAl, gBh, gBl);
        hidden_layer(wsu, (2 * L + 1) * 4096, (L == 0) ? b3 : b5, ln, gg,
                     gBh, gBl, gAh, gAl);
    }

    // ---- head: U^T = Wout^T @ G5 (jets 0,1,3); u0 -> LDS, f -> F frags ----
    const float l1v = l1p[0], l2v = l2p[0];
    u32x4 fhU[4], flU[4];
#pragma unroll
    for (int kt = 0; kt < 4; ++kt) {
        fhU[kt] = (u32x4){0u, 0u, 0u, 0u};
        flU[kt] = (u32x4){0u, 0u, 0u, 0u};
    }
#pragma unroll
    for (int jrt = 0; jrt < 7; ++jrt) {
        f32x4 a0A = {0.f, 0.f, 0.f, 0.f}, a0B = {0.f, 0.f, 0.f, 0.f};
        f32x4 a1A = {0.f, 0.f, 0.f, 0.f}, a1B = {0.f, 0.f, 0.f, 0.f};
        f32x4 a3A = {0.f, 0.f, 0.f, 0.f}, a3B = {0.f, 0.f, 0.f, 0.f};
#pragma unroll
        for (int krt = 0; krt < 2; ++krt) {
            s16x8 wh = *(const s16x8*)(wsu + WO_HI + (jrt * 2 + krt) * 512 + ln * 8);
            s16x8 wl = *(const s16x8*)(wsu + WO_LO + (jrt * 2 + krt) * 512 + ln * 8);
            s16x8 b0h = asfrag(gAh[krt][0]), b0l = asfrag(gAl[krt][0]);
            s16x8 b1h = asfrag(gAh[krt][1]), b1l = asfrag(gAl[krt][1]);
            s16x8 b3h = asfrag(gAh[krt][3]), b3l = asfrag(gAl[krt][3]);
            a0A = mm(wh, b0h, a0A); a0B = mm(wh, b0l, a0B); a0B = mm(wl, b0h, a0B);
            a1A = mm(wh, b1h, a1A); a1B = mm(wh, b1l, a1B); a1B = mm(wl, b1h, a1B);
            a3A = mm(wh, b3h, a3A); a3B = mm(wh, b3l, a3B); a3B = mm(wl, b3h, a3B);
        }
        float bo[4];
        if (jrt < 6) {
            float4 b4 = *(const float4*)(bout + 16 * jrt + 4 * gg);
            bo[0] = b4.x; bo[1] = b4.y; bo[2] = b4.z; bo[3] = b4.w;
        } else {
#pragma unroll
            for (int r = 0; r < 4; ++r) {
                int j = 96 + 4 * gg + r;
                bo[r] = (j < 100) ? bout[j] : 0.0f;
            }
        }
        float u0[4], fv[4];
#pragma unroll
        for (int r = 0; r < 4; ++r) {
            u0[r] = a0A[r] + a0B[r] + bo[r];
            fv[r] = -(l1v * u0[r]) * (a1A[r] + a1B[r]) - l2v * (a3A[r] + a3B[r]);
        }
        *(float4*)&so[cc * 116 + 16 * jrt + 4 * gg] =
            make_float4(u0[0], u0[1], u0[2], u0[3]);        // stage u0
        const int kt = jrt >> 1, p = jrt & 1;
        unsigned int hp0, lp0, hp1, lp1;
        cvt2(fv[0], fv[1], hp0, lp0);
        cvt2(fv[2], fv[3], hp1, lp1);
        fhU[kt][2 * p]     = hp0;
        fhU[kt][2 * p + 1] = hp1;
        flU[kt][2 * p]     = lp0;
        flU[kt][2 * p + 1] = lp1;
    }

    // ---- final: out^T = u0^T + Mdt^T @ F^T ----
#pragma unroll
    for (int jrt = 0; jrt < 7; ++jrt) {
        f32x4 accA = {0.f, 0.f, 0.f, 0.f}, accB = {0.f, 0.f, 0.f, 0.f};
#pragma unroll
        for (int kt = 0; kt < 4; ++kt) {
            s16x8 mh = *(const s16x8*)(wsu + MD_HI + (jrt * 4 + kt) * 512 + ln * 8);
            s16x8 ml = *(const s16x8*)(wsu + MD_LO + (jrt * 4 + kt) * 512 + ln * 8);
            s16x8 fb = asfrag(fhU[kt]);
            s16x8 fr = asfrag(flU[kt]);
            accA = mm(mh, fb, accA);
            accB = mm(mh, fr, accB);
            accB = mm(ml, fb, accB);
        }
        float* sp = &so[cc * 116 + 16 * jrt + 4 * gg];
        float4 u0v = *(const float4*)sp;                    // same-lane readback
        *(float4*)sp = make_float4(u0v.x + accA[0] + accB[0],
                                   u0v.y + accA[1] + accB[1],
                                   u0v.z + accA[2] + accB[2],
                                   u0v.w + accA[3] + accB[3]);
    }
    __syncthreads();

    // ---- coalesced store: per wave, lane = (sample s, quarter q) ----
    {
        int s = ln >> 2, q = ln & 3;
        int nidx = n0 + s;
        if (nidx < N) {
            float* op = out + (size_t)nidx * 100;
#pragma unroll
            for (int i2 = 0; i2 < 7; ++i2) {
                int j = 28 * q + 4 * i2;
                if (j < 100) {
                    float4 v = *(const float4*)&so[s * 116 + j];
                    *(float4*)(op + j) = v;
                }
            }
        }
    }
}

extern "C" void kernel_launch(void* const* d_in, const int* in_sizes, int n_in,
                              void* d_out, int out_size, void* d_ws, size_t ws_size,
                              hipStream_t stream)
{
    const float* X     = (const float*)d_in[0];
    const float* dt    = (const float*)d_in[1];
    const float* alpha = (const float*)d_in[2];
    const float* beta  = (const float*)d_in[3];
    const float* W1    = (const float*)d_in[4];
    const float* b1    = (const float*)d_in[5];
    const float* W2    = (const float*)d_in[6];
    const float* b2    = (const float*)d_in[7];
    const float* W3    = (const float*)d_in[8];
    const float* b3    = (const float*)d_in[9];
    const float* W4    = (const float*)d_in[10];
    const float* b4    = (const float*)d_in[11];
    const float* W5    = (const float*)d_in[12];
    const float* b5    = (const float*)d_in[13];
    const float* Wout  = (const float*)d_in[14];
    const float* bout  = (const float*)d_in[15];
    const float* l1    = (const float*)d_in[16];
    const float* l2    = (const float*)d_in[17];

    unsigned short* wsu = (unsigned short*)d_ws;
    int N = in_sizes[0];

    pinn_prep<<<148, 256, 0, stream>>>(alpha, beta, dt, W2, W3, W4, W5, Wout, wsu);

    int grid = (N + 31) / 32;
    pinn_main<<<grid, 128, 0, stream>>>(X, N, W1, b1, b2, b3, b4, b5,
                                        bout, l1, l2, wsu, (float*)d_out);
}

// Round 11
// 138.999 us; speedup vs baseline: 1.3355x; 1.0853x over previous
//
#include <hip/hip_runtime.h>

// PINN jets via MFMA, round 11: transposed network (zero cross-lane), fast
// K=32 op, slot-permuted K, PRECISION-TIERED term dropping.
//
// Error flow: out = u + dt*(f@M), f = -l1*u*u1 - l2*u3, dt=0.1, |M|~0.1,
// l2=0.0025. Jet-1 errors reach out attenuated ~100x; jets 2/3 only via
// l2*u3 (~1e4x). Tiering:
//   jet0 (u):   3-term (AhBh + AhBl + AlBh)  — direct output path
//   jet1 (u'):  2-term (AhBh + AlBh)         — value-lo dropped
//   jet2/3:     1-term (AhBh)                — pure bf16
//   head: a0 3-term, a1 2-term, a3 1-term; final: F 1-term, Mdt 2-term
// MFMA/wave 594 -> 364; jets 1-3 pack via single cvt_pk (no residual VALU).
//
// Slot map (operands agree; MFMA reduces over slots s = 8*gg+e):
//   neuron(krt, s) = 32*krt + 16*(e>>2) + 4*gg + (e&3)
// C/D output (col=lane&15, row=4*gg+reg, tile jrt) packs in-lane into
// next-layer B-frags: jrt=2*kd+p, regs q -> u32 slots 2p, 2p+1 of frag[kd].
// Weights pre-permuted into matching A-frag order (hi/lo) by pinn_prep.
//
// 256-thread blocks = 4 independent waves, 16 samples each.

typedef float f32x4 __attribute__((ext_vector_type(4)));
typedef short s16x8 __attribute__((ext_vector_type(8)));
typedef unsigned int u32x4 __attribute__((ext_vector_type(4)));

// ws layout (ushort units):
//   WhidT hi [l4][jrt4][krt2][lane64][e8] @ 0     (16384), lo @ 16384
//   WoutT hi [jrt7][krt2][lane][e8]      @ 32768  (7168),  lo @ 39936
//   MdtT  hi [jrt7][kt4][lane][e8]       @ 47104  (14336), lo @ 61440
constexpr int WH_LO = 16384, WO_HI = 32768, WO_LO = 39936;
constexpr int MD_HI = 47104, MD_LO = 61440;

__device__ __forceinline__ unsigned short f2b(float v) {
    unsigned int u = __builtin_bit_cast(unsigned int, v);
    unsigned int r = (u + 0x7FFFu + ((u >> 16) & 1u)) >> 16;   // RNE
    return (unsigned short)r;
}
__device__ __forceinline__ float b2f(unsigned short h) {
    return __builtin_bit_cast(float, (unsigned int)h << 16);
}
__device__ __forceinline__ unsigned int cvtpk(float lo, float hi) {
    unsigned int r;
    asm("v_cvt_pk_bf16_f32 %0, %1, %2" : "=v"(r) : "v"(lo), "v"(hi));
    return r;   // low16 = bf16(lo), high16 = bf16(hi)
}
__device__ __forceinline__ void cvt2(float v0, float v1,
                                     unsigned int& hp, unsigned int& lp) {
    hp = cvtpk(v0, v1);
    float r0 = v0 - __builtin_bit_cast(float, hp << 16);
    float r1 = v1 - __builtin_bit_cast(float, hp & 0xFFFF0000u);
    lp = cvtpk(r0, r1);
}
__device__ __forceinline__ s16x8 asfrag(u32x4 u) {
    return __builtin_bit_cast(s16x8, u);
}
__device__ __forceinline__ f32x4 mm(s16x8 a, s16x8 b, f32x4 c) {
    return __builtin_amdgcn_mfma_f32_16x16x32_bf16(a, b, c, 0, 0, 0);
}
__device__ __forceinline__ float ftanh(float z) {
    float e = __expf(2.0f * z);
    float r = __builtin_amdgcn_rcpf(e + 1.0f);
    return fmaf(-2.0f, r, 1.0f);
}

__global__ __launch_bounds__(256) void pinn_prep(
    const float* __restrict__ alpha, const float* __restrict__ beta,
    const float* __restrict__ dtp,
    const float* __restrict__ W2, const float* __restrict__ W3,
    const float* __restrict__ W4, const float* __restrict__ W5,
    const float* __restrict__ Wout, unsigned short* __restrict__ wsu)
{
    int i = blockIdx.x * 256 + threadIdx.x;
    float v; int hi_off, lo_off;
    if (i < 16384) {                                   // hidden W^T A-frags
        int l = i >> 12, r = i & 4095;
        int t = r >> 9, jrt = t >> 1, krt = t & 1;
        int lane = (r >> 3) & 63, e = r & 7;
        int gg = lane >> 4;
        int j = 16 * jrt + (lane & 15);
        int n = 32 * krt + 16 * (e >> 2) + 4 * gg + (e & 3);
        const float* W = (l == 0) ? W2 : (l == 1) ? W3 : (l == 2) ? W4 : W5;
        v = (n < 50 && j < 50) ? W[n * 50 + j] : 0.0f;
        hi_off = i; lo_off = i + WH_LO;
    } else if (i < 23552) {                            // Wout^T A-frags
        int r = i - 16384;
        int t = r >> 9, jrt = t >> 1, krt = t & 1;
        int lane = (r >> 3) & 63, e = r & 7;
        int gg = lane >> 4;
        int j = 16 * jrt + (lane & 15);
        int n = 32 * krt + 16 * (e >> 2) + 4 * gg + (e & 3);
        v = (n < 50 && j < 100) ? Wout[n * 100 + j] : 0.0f;
        hi_off = WO_HI + r; lo_off = WO_LO + r;
    } else if (i < 37888) {                            // Mdt^T A-frags
        int r = i - 23552;
        int t = r >> 9, jrt = t >> 2, kt = t & 3;
        int lane = (r >> 3) & 63, e = r & 7;
        int gg = lane >> 4;
        int j = 16 * jrt + (lane & 15);
        int k = 32 * kt + 16 * (e >> 2) + 4 * gg + (e & 3);
        v = (j < 100 && k < 100) ? dtp[0] * (beta[k] - alpha[j * 100 + k]) : 0.0f;
        hi_off = MD_HI + r; lo_off = MD_LO + r;
    } else return;
    unsigned short h = f2b(v);
    wsu[hi_off] = h;
    wsu[lo_off] = f2b(v - b2f(h));
}

// One hidden layer, precision-tiered. gh = all-jet hi frags, gl0 = jet-0 lo.
__device__ __forceinline__ void hidden_layer(
    const unsigned short* __restrict__ wsu, int Lb,
    const float* __restrict__ bias, int ln, int gg,
    const u32x4 (&gh)[2][4], const u32x4 (&gl0)[2],
    u32x4 (&nh)[2][4], u32x4 (&nl0)[2])
{
#pragma unroll
    for (int kd = 0; kd < 2; ++kd) {
#pragma unroll
        for (int ct = 0; ct < 4; ++ct) nh[kd][ct] = (u32x4){0u, 0u, 0u, 0u};
        nl0[kd] = (u32x4){0u, 0u, 0u, 0u};
    }
#pragma unroll
    for (int jrt = 0; jrt < 4; ++jrt) {
        f32x4 accA[4], accB0 = {0.f, 0.f, 0.f, 0.f}, accB1 = {0.f, 0.f, 0.f, 0.f};
#pragma unroll
        for (int ct = 0; ct < 4; ++ct) accA[ct] = (f32x4){0.f, 0.f, 0.f, 0.f};
#pragma unroll
        for (int krt = 0; krt < 2; ++krt) {
            s16x8 wh = *(const s16x8*)(wsu + Lb + (jrt * 2 + krt) * 512 + ln * 8);
            s16x8 wl = *(const s16x8*)(wsu + WH_LO + Lb + (jrt * 2 + krt) * 512 + ln * 8);
            s16x8 b0h = asfrag(gh[krt][0]);
            s16x8 b0l = asfrag(gl0[krt]);
            s16x8 b1h = asfrag(gh[krt][1]);
            accA[0] = mm(wh, b0h, accA[0]);                 // jet0: 3-term
            accB0   = mm(wh, b0l, accB0);
            accB0   = mm(wl, b0h, accB0);
            accA[1] = mm(wh, b1h, accA[1]);                 // jet1: 2-term
            accB1   = mm(wl, b1h, accB1);
            accA[2] = mm(wh, asfrag(gh[krt][2]), accA[2]);  // jet2: 1-term
            accA[3] = mm(wh, asfrag(gh[krt][3]), accA[3]);  // jet3: 1-term
        }
        float bv[4];
        if (jrt < 3) {
            float4 b4 = *(const float4*)(bias + 16 * jrt + 4 * gg);
            bv[0] = b4.x; bv[1] = b4.y; bv[2] = b4.z; bv[3] = b4.w;
        } else {
#pragma unroll
            for (int r = 0; r < 4; ++r) {
                int j = 48 + 4 * gg + r;
                bv[r] = (j < 50) ? bias[j] : 0.0f;
            }
        }
        float m[4][4];
#pragma unroll
        for (int r = 0; r < 4; ++r) {
            float z0 = accA[0][r] + accB0[r] + bv[r];
            float z1 = accA[1][r] + accB1[r];
            float z2 = accA[2][r];
            float z3 = accA[3][r];
            float t  = ftanh(z0);
            float sd = fmaf(-t, t, 1.0f);
            float c2 = -2.0f * t * sd;
            float c3 = -2.0f * sd * fmaf(3.0f, sd, -2.0f);
            float z1sq = z1 * z1;
            m[0][r] = t;
            m[1][r] = sd * z1;
            m[2][r] = fmaf(c2, z1sq, sd * z2);
            m[3][r] = fmaf(c3, z1sq * z1, fmaf(3.0f * c2, z1 * z2, sd * z3));
        }
        const int kd = jrt >> 1, p = jrt & 1;
        {   // jet0: hi + lo
            unsigned int hp0, lp0, hp1, lp1;
            cvt2(m[0][0], m[0][1], hp0, lp0);
            cvt2(m[0][2], m[0][3], hp1, lp1);
            nh[kd][0][2 * p]     = hp0;
            nh[kd][0][2 * p + 1] = hp1;
            nl0[kd][2 * p]       = lp0;
            nl0[kd][2 * p + 1]   = lp1;
        }
#pragma unroll
        for (int ct = 1; ct < 4; ++ct) {                    // jets 1-3: hi only
            nh[kd][ct][2 * p]     = cvtpk(m[ct][0], m[ct][1]);
            nh[kd][ct][2 * p + 1] = cvtpk(m[ct][2], m[ct][3]);
        }
    }
}

__global__ __launch_bounds__(256) void pinn_main(
    const float* __restrict__ X, int N,
    const float* __restrict__ W1, const float* __restrict__ b1,
    const float* __restrict__ b2, const float* __restrict__ b3,
    const float* __restrict__ b4, const float* __restrict__ b5,
    const float* __restrict__ bout,
    const float* __restrict__ l1p, const float* __restrict__ l2p,
    const unsigned short* __restrict__ wsu,
    float* __restrict__ out)
{
    __shared__ __align__(16) float soutA[4][16 * 116];
    const int tid = threadIdx.x;
    const int wv = tid >> 6, ln = tid & 63;
    const int cc = ln & 15, gg = ln >> 4;
    const int n0 = blockIdx.x * 64 + wv * 16;
    float* so = soutA[wv];

    u32x4 gAh[2][4], gAl0[2], gBh[2][4], gBl0[2];
#pragma unroll
    for (int krt = 0; krt < 2; ++krt) {
#pragma unroll
        for (int ct = 0; ct < 4; ++ct) gAh[krt][ct] = (u32x4){0u, 0u, 0u, 0u};
        gAl0[krt] = (u32x4){0u, 0u, 0u, 0u};
    }

    // ---- layer 1: width 1 -> 50, jets (x,1,0,0), in-lane packing ----
    float x = (n0 + cc < N) ? X[n0 + cc] : 0.0f;
#pragma unroll
    for (int krt = 0; krt < 2; ++krt)
#pragma unroll
        for (int jf = 0; jf < 2; ++jf) {
            float m[4][4];
#pragma unroll
            for (int q = 0; q < 4; ++q) {
                int n = 32 * krt + 16 * jf + 4 * gg + q;
                float w = (n < 50) ? W1[n] : 0.0f;
                float b = (n < 50) ? b1[n] : 0.0f;
                float z0 = fmaf(x, w, b);
                float t  = ftanh(z0);
                float sd = fmaf(-t, t, 1.0f);
                float c2 = -2.0f * t * sd;
                float c3 = -2.0f * sd * fmaf(3.0f, sd, -2.0f);
                float w2 = w * w;
                m[0][q] = t; m[1][q] = sd * w; m[2][q] = c2 * w2; m[3][q] = c3 * w2 * w;
            }
            {
                unsigned int hp0, lp0, hp1, lp1;
                cvt2(m[0][0], m[0][1], hp0, lp0);
                cvt2(m[0][2], m[0][3], hp1, lp1);
                gAh[krt][0][2 * jf]     = hp0;
                gAh[krt][0][2 * jf + 1] = hp1;
                gAl0[krt][2 * jf]       = lp0;
                gAl0[krt][2 * jf + 1]   = lp1;
            }
#pragma unroll
            for (int ct = 1; ct < 4; ++ct) {
                gAh[krt][ct][2 * jf]     = cvtpk(m[ct][0], m[ct][1]);
                gAh[krt][ct][2 * jf + 1] = cvtpk(m[ct][2], m[ct][3]);
            }
        }

    // ---- layers 2..5 (A->B->A->B->A) ----
#pragma unroll 1
    for (int L = 0; L < 2; ++L) {
        hidden_layer(wsu, (2 * L) * 4096,     (L == 0) ? b2 : b4, ln, gg,
                     gAh, gAl0, gBh, gBl0);
        hidden_layer(wsu, (2 * L + 1) * 4096, (L == 0) ? b3 : b5, ln, gg,
                     gBh, gBl0, gAh, gAl0);
    }

    // ---- head: a0 3-term, a1 2-term, a3 1-term; u0 -> LDS, f -> F frags ----
    const float l1v = l1p[0], l2v = l2p[0];
    u32x4 fhU[4];
#pragma unroll
    for (int kt = 0; kt < 4; ++kt) fhU[kt] = (u32x4){0u, 0u, 0u, 0u};
#pragma unroll
    for (int jrt = 0; jrt < 7; ++jrt) {
        f32x4 a0A = {0.f, 0.f, 0.f, 0.f}, a0B = {0.f, 0.f, 0.f, 0.f};
        f32x4 a1A = {0.f, 0.f, 0.f, 0.f}, a1B = {0.f, 0.f, 0.f, 0.f};
        f32x4 a3A = {0.f, 0.f, 0.f, 0.f};
#pragma unroll
        for (int krt = 0; krt < 2; ++krt) {
            s16x8 wh = *(const s16x8*)(wsu + WO_HI + (jrt * 2 + krt) * 512 + ln * 8);
            s16x8 wl = *(const s16x8*)(wsu + WO_LO + (jrt * 2 + krt) * 512 + ln * 8);
            s16x8 b0h = asfrag(gAh[krt][0]);
            s16x8 b0l = asfrag(gAl0[krt]);
            s16x8 b1h = asfrag(gAh[krt][1]);
            a0A = mm(wh, b0h, a0A);
            a0B = mm(wh, b0l, a0B);
            a0B = mm(wl, b0h, a0B);
            a1A = mm(wh, b1h, a1A);
            a1B = mm(wl, b1h, a1B);
            a3A = mm(wh, asfrag(gAh[krt][3]), a3A);
        }
        float bo[4];
        if (jrt < 6) {
            float4 b4 = *(const float4*)(bout + 16 * jrt + 4 * gg);
            bo[0] = b4.x; bo[1] = b4.y; bo[2] = b4.z; bo[3] = b4.w;
        } else {
#pragma unroll
            for (int r = 0; r < 4; ++r) {
                int j = 96 + 4 * gg + r;
                bo[r] = (j < 100) ? bout[j] : 0.0f;
            }
        }
        float u0[4], fv[4];
#pragma unroll
        for (int r = 0; r < 4; ++r) {
            u0[r] = a0A[r] + a0B[r] + bo[r];
            fv[r] = -(l1v * u0[r]) * (a1A[r] + a1B[r]) - l2v * a3A[r];
        }
        *(float4*)&so[cc * 116 + 16 * jrt + 4 * gg] =
            make_float4(u0[0], u0[1], u0[2], u0[3]);        // stage u0
        const int kt = jrt >> 1, p = jrt & 1;
        fhU[kt][2 * p]     = cvtpk(fv[0], fv[1]);
        fhU[kt][2 * p + 1] = cvtpk(fv[2], fv[3]);
    }

    // ---- final: out^T = u0^T + Mdt^T @ F^T (F 1-term, Mdt 2-term) ----
#pragma unroll
    for (int jrt = 0; jrt < 7; ++jrt) {
        f32x4 accA = {0.f, 0.f, 0.f, 0.f}, accB = {0.f, 0.f, 0.f, 0.f};
#pragma unroll
        for (int kt = 0; kt < 4; ++kt) {
            s16x8 mh = *(const s16x8*)(wsu + MD_HI + (jrt * 4 + kt) * 512 + ln * 8);
            s16x8 ml = *(const s16x8*)(wsu + MD_LO + (jrt * 4 + kt) * 512 + ln * 8);
            s16x8 fb = asfrag(fhU[kt]);
            accA = mm(mh, fb, accA);
            accB = mm(ml, fb, accB);
        }
        float* sp = &so[cc * 116 + 16 * jrt + 4 * gg];
        float4 u0v = *(const float4*)sp;                    // same-lane readback
        *(float4*)sp = make_float4(u0v.x + accA[0] + accB[0],
                                   u0v.y + accA[1] + accB[1],
                                   u0v.z + accA[2] + accB[2],
                                   u0v.w + accA[3] + accB[3]);
    }
    __syncthreads();

    // ---- coalesced store: per wave, lane = (sample s, quarter q) ----
    {
        int s = ln >> 2, q = ln & 3;
        int nidx = n0 + s;
        if (nidx < N) {
            float* op = out + (size_t)nidx * 100;
#pragma unroll
            for (int i2 = 0; i2 < 7; ++i2) {
                int j = 28 * q + 4 * i2;
                if (j < 100) {
                    float4 v = *(const float4*)&so[s * 116 + j];
                    *(float4*)(op + j) = v;
                }
            }
        }
    }
}

extern "C" void kernel_launch(void* const* d_in, const int* in_sizes, int n_in,
                              void* d_out, int out_size, void* d_ws, size_t ws_size,
                              hipStream_t stream)
{
    const float* X     = (const float*)d_in[0];
    const float* dt    = (const float*)d_in[1];
    const float* alpha = (const float*)d_in[2];
    const float* beta  = (const float*)d_in[3];
    const float* W1    = (const float*)d_in[4];
    const float* b1    = (const float*)d_in[5];
    const float* W2    = (const float*)d_in[6];
    const float* b2    = (const float*)d_in[7];
    const float* W3    = (const float*)d_in[8];
    const float* b3    = (const float*)d_in[9];
    const float* W4    = (const float*)d_in[10];
    const float* b4    = (const float*)d_in[11];
    const float* W5    = (const float*)d_in[12];
    const float* b5    = (const float*)d_in[13];
    const float* Wout  = (const float*)d_in[14];
    const float* bout  = (const float*)d_in[15];
    const float* l1    = (const float*)d_in[16];
    const float* l2    = (const float*)d_in[17];

    unsigned short* wsu = (unsigned short*)d_ws;
    int N = in_sizes[0];

    pinn_prep<<<148, 256, 0, stream>>>(alpha, beta, dt, W2, W3, W4, W5, Wout, wsu);

    int grid = (N + 63) / 64;
    pinn_main<<<grid, 256, 0, stream>>>(X, N, W1, b1, b2, b3, b4, b5,
                                        bout, l1, l2, wsu, (float*)d_out);
}

// Round 12
// 117.447 us; speedup vs baseline: 1.5806x; 1.1835x over previous
//
#include <hip/hip_runtime.h>

// PINN jets via MFMA, round 12: transposed network (zero cross-lane), fast
// K=32 op, slot-permuted K, precision-tiered terms; LATENCY-FILL round:
//   - 128-thread blocks (2 waves), LDS 14.8 KB -> ~11 blocks/CU capacity
//   - __launch_bounds__(128,4): min 4 waves/EU (VGPR cap 128 >> true ~70)
//   - all >=4-deep MFMA chains split into independent accumulators
//
// Tiering (error flow: out = u + dt*(f@M), dt=0.1, |M|~0.1, l2=0.0025):
//   jet0 3-term, jet1 2-term, jet2/3 1-term; head a0 3/a1 2/a3 1; final F 1, Mdt 2.
// Slot map: neuron(krt, s=8gg+e) = 32*krt + 16*(e>>2) + 4*gg + (e&3); C/D of
// tile jrt=2kd+p packs in-lane into B-frag[kd] u32 slots 2p,2p+1 (cvt_pk).

typedef float f32x4 __attribute__((ext_vector_type(4)));
typedef short s16x8 __attribute__((ext_vector_type(8)));
typedef unsigned int u32x4 __attribute__((ext_vector_type(4)));

// ws layout (ushort units):
constexpr int WH_LO = 16384, WO_HI = 32768, WO_LO = 39936;
constexpr int MD_HI = 47104, MD_LO = 61440;

__device__ __forceinline__ unsigned short f2b(float v) {
    unsigned int u = __builtin_bit_cast(unsigned int, v);
    unsigned int r = (u + 0x7FFFu + ((u >> 16) & 1u)) >> 16;   // RNE
    return (unsigned short)r;
}
__device__ __forceinline__ float b2f(unsigned short h) {
    return __builtin_bit_cast(float, (unsigned int)h << 16);
}
__device__ __forceinline__ unsigned int cvtpk(float lo, float hi) {
    unsigned int r;
    asm("v_cvt_pk_bf16_f32 %0, %1, %2" : "=v"(r) : "v"(lo), "v"(hi));
    return r;   // low16 = bf16(lo), high16 = bf16(hi)
}
__device__ __forceinline__ void cvt2(float v0, float v1,
                                     unsigned int& hp, unsigned int& lp) {
    hp = cvtpk(v0, v1);
    float r0 = v0 - __builtin_bit_cast(float, hp << 16);
    float r1 = v1 - __builtin_bit_cast(float, hp & 0xFFFF0000u);
    lp = cvtpk(r0, r1);
}
__device__ __forceinline__ s16x8 asfrag(u32x4 u) {
    return __builtin_bit_cast(s16x8, u);
}
__device__ __forceinline__ f32x4 mm(s16x8 a, s16x8 b, f32x4 c) {
    return __builtin_amdgcn_mfma_f32_16x16x32_bf16(a, b, c, 0, 0, 0);
}
__device__ __forceinline__ float ftanh(float z) {
    float e = __expf(2.0f * z);
    float r = __builtin_amdgcn_rcpf(e + 1.0f);
    return fmaf(-2.0f, r, 1.0f);
}

__global__ __launch_bounds__(256) void pinn_prep(
    const float* __restrict__ alpha, const float* __restrict__ beta,
    const float* __restrict__ dtp,
    const float* __restrict__ W2, const float* __restrict__ W3,
    const float* __restrict__ W4, const float* __restrict__ W5,
    const float* __restrict__ Wout, unsigned short* __restrict__ wsu)
{
    int i = blockIdx.x * 256 + threadIdx.x;
    float v; int hi_off, lo_off;
    if (i < 16384) {                                   // hidden W^T A-frags
        int l = i >> 12, r = i & 4095;
        int t = r >> 9, jrt = t >> 1, krt = t & 1;
        int lane = (r >> 3) & 63, e = r & 7;
        int gg = lane >> 4;
        int j = 16 * jrt + (lane & 15);
        int n = 32 * krt + 16 * (e >> 2) + 4 * gg + (e & 3);
        const float* W = (l == 0) ? W2 : (l == 1) ? W3 : (l == 2) ? W4 : W5;
        v = (n < 50 && j < 50) ? W[n * 50 + j] : 0.0f;
        hi_off = i; lo_off = i + WH_LO;
    } else if (i < 23552) {                            // Wout^T A-frags
        int r = i - 16384;
        int t = r >> 9, jrt = t >> 1, krt = t & 1;
        int lane = (r >> 3) & 63, e = r & 7;
        int gg = lane >> 4;
        int j = 16 * jrt + (lane & 15);
        int n = 32 * krt + 16 * (e >> 2) + 4 * gg + (e & 3);
        v = (n < 50 && j < 100) ? Wout[n * 100 + j] : 0.0f;
        hi_off = WO_HI + r; lo_off = WO_LO + r;
    } else if (i < 37888) {                            // Mdt^T A-frags
        int r = i - 23552;
        int t = r >> 9, jrt = t >> 2, kt = t & 3;
        int lane = (r >> 3) & 63, e = r & 7;
        int gg = lane >> 4;
        int j = 16 * jrt + (lane & 15);
        int k = 32 * kt + 16 * (e >> 2) + 4 * gg + (e & 3);
        v = (j < 100 && k < 100) ? dtp[0] * (beta[k] - alpha[j * 100 + k]) : 0.0f;
        hi_off = MD_HI + r; lo_off = MD_LO + r;
    } else return;
    unsigned short h = f2b(v);
    wsu[hi_off] = h;
    wsu[lo_off] = f2b(v - b2f(h));
}

// One hidden layer, precision-tiered, split accumulator chains (max 2-deep).
__device__ __forceinline__ void hidden_layer(
    const unsigned short* __restrict__ wsu, int Lb,
    const float* __restrict__ bias, int ln, int gg,
    const u32x4 (&gh)[2][4], const u32x4 (&gl0)[2],
    u32x4 (&nh)[2][4], u32x4 (&nl0)[2])
{
#pragma unroll
    for (int kd = 0; kd < 2; ++kd) {
#pragma unroll
        for (int ct = 0; ct < 4; ++ct) nh[kd][ct] = (u32x4){0u, 0u, 0u, 0u};
        nl0[kd] = (u32x4){0u, 0u, 0u, 0u};
    }
#pragma unroll
    for (int jrt = 0; jrt < 4; ++jrt) {
        f32x4 accA[4];
        f32x4 accB0a = {0.f, 0.f, 0.f, 0.f}, accB0b = {0.f, 0.f, 0.f, 0.f};
        f32x4 accB1  = {0.f, 0.f, 0.f, 0.f};
#pragma unroll
        for (int ct = 0; ct < 4; ++ct) accA[ct] = (f32x4){0.f, 0.f, 0.f, 0.f};
#pragma unroll
        for (int krt = 0; krt < 2; ++krt) {
            s16x8 wh = *(const s16x8*)(wsu + Lb + (jrt * 2 + krt) * 512 + ln * 8);
            s16x8 wl = *(const s16x8*)(wsu + WH_LO + Lb + (jrt * 2 + krt) * 512 + ln * 8);
            s16x8 b0h = asfrag(gh[krt][0]);
            s16x8 b0l = asfrag(gl0[krt]);
            s16x8 b1h = asfrag(gh[krt][1]);
            accA[0] = mm(wh, b0h, accA[0]);                 // jet0: 3-term
            accB0a  = mm(wh, b0l, accB0a);
            accB0b  = mm(wl, b0h, accB0b);
            accA[1] = mm(wh, b1h, accA[1]);                 // jet1: 2-term
            accB1   = mm(wl, b1h, accB1);
            accA[2] = mm(wh, asfrag(gh[krt][2]), accA[2]);  // jet2: 1-term
            accA[3] = mm(wh, asfrag(gh[krt][3]), accA[3]);  // jet3: 1-term
        }
        float bv[4];
        if (jrt < 3) {
            float4 b4 = *(const float4*)(bias + 16 * jrt + 4 * gg);
            bv[0] = b4.x; bv[1] = b4.y; bv[2] = b4.z; bv[3] = b4.w;
        } else {
#pragma unroll
            for (int r = 0; r < 4; ++r) {
                int j = 48 + 4 * gg + r;
                bv[r] = (j < 50) ? bias[j] : 0.0f;
            }
        }
        float m[4][4];
#pragma unroll
        for (int r = 0; r < 4; ++r) {
            float z0 = (accA[0][r] + accB0a[r]) + (accB0b[r] + bv[r]);
            float z1 = accA[1][r] + accB1[r];
            float z2 = accA[2][r];
            float z3 = accA[3][r];
            float t  = ftanh(z0);
            float sd = fmaf(-t, t, 1.0f);
            float c2 = -2.0f * t * sd;
            float c3 = -2.0f * sd * fmaf(3.0f, sd, -2.0f);
            float z1sq = z1 * z1;
            m[0][r] = t;
            m[1][r] = sd * z1;
            m[2][r] = fmaf(c2, z1sq, sd * z2);
            m[3][r] = fmaf(c3, z1sq * z1, fmaf(3.0f * c2, z1 * z2, sd * z3));
        }
        const int kd = jrt >> 1, p = jrt & 1;
        {   // jet0: hi + lo
            unsigned int hp0, lp0, hp1, lp1;
            cvt2(m[0][0], m[0][1], hp0, lp0);
            cvt2(m[0][2], m[0][3], hp1, lp1);
            nh[kd][0][2 * p]     = hp0;
            nh[kd][0][2 * p + 1] = hp1;
            nl0[kd][2 * p]       = lp0;
            nl0[kd][2 * p + 1]   = lp1;
        }
#pragma unroll
        for (int ct = 1; ct < 4; ++ct) {                    // jets 1-3: hi only
            nh[kd][ct][2 * p]     = cvtpk(m[ct][0], m[ct][1]);
            nh[kd][ct][2 * p + 1] = cvtpk(m[ct][2], m[ct][3]);
        }
    }
}

__global__ __launch_bounds__(128, 4) void pinn_main(
    const float* __restrict__ X, int N,
    const float* __restrict__ W1, const float* __restrict__ b1,
    const float* __restrict__ b2, const float* __restrict__ b3,
    const float* __restrict__ b4, const float* __restrict__ b5,
    const float* __restrict__ bout,
    const float* __restrict__ l1p, const float* __restrict__ l2p,
    const unsigned short* __restrict__ wsu,
    float* __restrict__ out)
{
    __shared__ __align__(16) float soutA[2][16 * 116];
    const int tid = threadIdx.x;
    const int wv = tid >> 6, ln = tid & 63;
    const int cc = ln & 15, gg = ln >> 4;
    const int n0 = blockIdx.x * 32 + wv * 16;
    float* so = soutA[wv];

    u32x4 gAh[2][4], gAl0[2], gBh[2][4], gBl0[2];
#pragma unroll
    for (int krt = 0; krt < 2; ++krt) {
#pragma unroll
        for (int ct = 0; ct < 4; ++ct) gAh[krt][ct] = (u32x4){0u, 0u, 0u, 0u};
        gAl0[krt] = (u32x4){0u, 0u, 0u, 0u};
    }

    // ---- layer 1: width 1 -> 50, jets (x,1,0,0), in-lane packing ----
    float x = (n0 + cc < N) ? X[n0 + cc] : 0.0f;
#pragma unroll
    for (int krt = 0; krt < 2; ++krt)
#pragma unroll
        for (int jf = 0; jf < 2; ++jf) {
            float m[4][4];
#pragma unroll
            for (int q = 0; q < 4; ++q) {
                int n = 32 * krt + 16 * jf + 4 * gg + q;
                float w = (n < 50) ? W1[n] : 0.0f;
                float b = (n < 50) ? b1[n] : 0.0f;
                float z0 = fmaf(x, w, b);
                float t  = ftanh(z0);
                float sd = fmaf(-t, t, 1.0f);
                float c2 = -2.0f * t * sd;
                float c3 = -2.0f * sd * fmaf(3.0f, sd, -2.0f);
                float w2 = w * w;
                m[0][q] = t; m[1][q] = sd * w; m[2][q] = c2 * w2; m[3][q] = c3 * w2 * w;
            }
            {
                unsigned int hp0, lp0, hp1, lp1;
                cvt2(m[0][0], m[0][1], hp0, lp0);
                cvt2(m[0][2], m[0][3], hp1, lp1);
                gAh[krt][0][2 * jf]     = hp0;
                gAh[krt][0][2 * jf + 1] = hp1;
                gAl0[krt][2 * jf]       = lp0;
                gAl0[krt][2 * jf + 1]   = lp1;
            }
#pragma unroll
            for (int ct = 1; ct < 4; ++ct) {
                gAh[krt][ct][2 * jf]     = cvtpk(m[ct][0], m[ct][1]);
                gAh[krt][ct][2 * jf + 1] = cvtpk(m[ct][2], m[ct][3]);
            }
        }

    // ---- layers 2..5 (A->B->A->B->A) ----
#pragma unroll 1
    for (int L = 0; L < 2; ++L) {
        hidden_layer(wsu, (2 * L) * 4096,     (L == 0) ? b2 : b4, ln, gg,
                     gAh, gAl0, gBh, gBl0);
        hidden_layer(wsu, (2 * L + 1) * 4096, (L == 0) ? b3 : b5, ln, gg,
                     gBh, gBl0, gAh, gAl0);
    }

    // ---- head: a0 3-term (split chains), a1 2-term, a3 1-term ----
    const float l1v = l1p[0], l2v = l2p[0];
    u32x4 fhU[4];
#pragma unroll
    for (int kt = 0; kt < 4; ++kt) fhU[kt] = (u32x4){0u, 0u, 0u, 0u};
#pragma unroll
    for (int jrt = 0; jrt < 7; ++jrt) {
        f32x4 a0A = {0.f, 0.f, 0.f, 0.f}, a0B = {0.f, 0.f, 0.f, 0.f};
        f32x4 a0C = {0.f, 0.f, 0.f, 0.f};
        f32x4 a1A = {0.f, 0.f, 0.f, 0.f}, a1B = {0.f, 0.f, 0.f, 0.f};
        f32x4 a3A = {0.f, 0.f, 0.f, 0.f};
#pragma unroll
        for (int krt = 0; krt < 2; ++krt) {
            s16x8 wh = *(const s16x8*)(wsu + WO_HI + (jrt * 2 + krt) * 512 + ln * 8);
            s16x8 wl = *(const s16x8*)(wsu + WO_LO + (jrt * 2 + krt) * 512 + ln * 8);
            s16x8 b0h = asfrag(gAh[krt][0]);
            s16x8 b0l = asfrag(gAl0[krt]);
            s16x8 b1h = asfrag(gAh[krt][1]);
            a0A = mm(wh, b0h, a0A);
            a0B = mm(wh, b0l, a0B);
            a0C = mm(wl, b0h, a0C);
            a1A = mm(wh, b1h, a1A);
            a1B = mm(wl, b1h, a1B);
            a3A = mm(wh, asfrag(gAh[krt][3]), a3A);
        }
        float bo[4];
        if (jrt < 6) {
            float4 b4 = *(const float4*)(bout + 16 * jrt + 4 * gg);
            bo[0] = b4.x; bo[1] = b4.y; bo[2] = b4.z; bo[3] = b4.w;
        } else {
#pragma unroll
            for (int r = 0; r < 4; ++r) {
                int j = 96 + 4 * gg + r;
                bo[r] = (j < 100) ? bout[j] : 0.0f;
            }
        }
        float u0[4], fv[4];
#pragma unroll
        for (int r = 0; r < 4; ++r) {
            u0[r] = (a0A[r] + a0B[r]) + (a0C[r] + bo[r]);
            fv[r] = -(l1v * u0[r]) * (a1A[r] + a1B[r]) - l2v * a3A[r];
        }
        *(float4*)&so[cc * 116 + 16 * jrt + 4 * gg] =
            make_float4(u0[0], u0[1], u0[2], u0[3]);        // stage u0
        const int kt = jrt >> 1, p = jrt & 1;
        fhU[kt][2 * p]     = cvtpk(fv[0], fv[1]);
        fhU[kt][2 * p + 1] = cvtpk(fv[2], fv[3]);
    }

    // ---- final: out^T = u0^T + Mdt^T @ F^T (F 1-term, Mdt 2-term) ----
#pragma unroll
    for (int jrt = 0; jrt < 7; ++jrt) {
        f32x4 accA = {0.f, 0.f, 0.f, 0.f}, accB = {0.f, 0.f, 0.f, 0.f};
        f32x4 accC = {0.f, 0.f, 0.f, 0.f}, accD = {0.f, 0.f, 0.f, 0.f};
#pragma unroll
        for (int kt = 0; kt < 4; ++kt) {
            s16x8 mh = *(const s16x8*)(wsu + MD_HI + (jrt * 4 + kt) * 512 + ln * 8);
            s16x8 ml = *(const s16x8*)(wsu + MD_LO + (jrt * 4 + kt) * 512 + ln * 8);
            s16x8 fb = asfrag(fhU[kt]);
            if (kt & 1) { accC = mm(mh, fb, accC); accD = mm(ml, fb, accD); }
            else        { accA = mm(mh, fb, accA); accB = mm(ml, fb, accB); }
        }
        float* sp = &so[cc * 116 + 16 * jrt + 4 * gg];
        float4 u0v = *(const float4*)sp;                    // same-lane readback
        *(float4*)sp = make_float4(u0v.x + (accA[0] + accB[0]) + (accC[0] + accD[0]),
                                   u0v.y + (accA[1] + accB[1]) + (accC[1] + accD[1]),
                                   u0v.z + (accA[2] + accB[2]) + (accC[2] + accD[2]),
                                   u0v.w + (accA[3] + accB[3]) + (accC[3] + accD[3]));
    }
    __syncthreads();

    // ---- coalesced store: per wave, lane = (sample s, quarter q) ----
    {
        int s = ln >> 2, q = ln & 3;
        int nidx = n0 + s;
        if (nidx < N) {
            float* op = out + (size_t)nidx * 100;
#pragma unroll
            for (int i2 = 0; i2 < 7; ++i2) {
                int j = 28 * q + 4 * i2;
                if (j < 100) {
                    float4 v = *(const float4*)&so[s * 116 + j];
                    *(float4*)(op + j) = v;
                }
            }
        }
    }
}

extern "C" void kernel_launch(void* const* d_in, const int* in_sizes, int n_in,
                              void* d_out, int out_size, void* d_ws, size_t ws_size,
                              hipStream_t stream)
{
    const float* X     = (const float*)d_in[0];
    const float* dt    = (const float*)d_in[1];
    const float* alpha = (const float*)d_in[2];
    const float* beta  = (const float*)d_in[3];
    const float* W1    = (const float*)d_in[4];
    const float* b1    = (const float*)d_in[5];
    const float* W2    = (const float*)d_in[6];
    const float* b2    = (const float*)d_in[7];
    const float* W3    = (const float*)d_in[8];
    const float* b3    = (const float*)d_in[9];
    const float* W4    = (const float*)d_in[10];
    const float* b4    = (const float*)d_in[11];
    const float* W5    = (const float*)d_in[12];
    const float* b5    = (const float*)d_in[13];
    const float* Wout  = (const float*)d_in[14];
    const float* bout  = (const float*)d_in[15];
    const float* l1    = (const float*)d_in[16];
    const float* l2    = (const float*)d_in[17];

    unsigned short* wsu = (unsigned short*)d_ws;
    int N = in_sizes[0];

    pinn_prep<<<148, 256, 0, stream>>>(alpha, beta, dt, W2, W3, W4, W5, Wout, wsu);

    int grid = (N + 31) / 32;
    pinn_main<<<grid, 128, 0, stream>>>(X, N, W1, b1, b2, b3, b4, b5,
                                        bout, l1, l2, wsu, (float*)d_out);
}

// Round 15
// 110.825 us; speedup vs baseline: 1.6751x; 1.0598x over previous
//
#include <hip/hip_runtime.h>

// PINN jets via MFMA, round 15: EXACT r12 arithmetic (passed, absmax at bf16
// floor) with ONLY the zero-LDS substitution applied:
//   - u0 kept in u0s[7][4] registers (was LDS so[] staging)
//   - final accumulates and stores directly to out (one float4 per jrt)
//   - no barrier, no LDS, no second store loop
// Everything else byte-identical to r12: 128-thread/2-wave blocks,
// __launch_bounds__(128,4), full pad compute (NO static skips), tiering
// jet0 3-term / jet1 2-term / jet2,3 1-term; head a0 3/a1 2/a3 1;
// final F 1-term, Mdt 2-term. This isolates the r13/r14 regression source.

typedef float f32x4 __attribute__((ext_vector_type(4)));
typedef short s16x8 __attribute__((ext_vector_type(8)));
typedef unsigned int u32x4 __attribute__((ext_vector_type(4)));

// ws layout (ushort units):
constexpr int WH_LO = 16384, WO_HI = 32768, WO_LO = 39936;
constexpr int MD_HI = 47104, MD_LO = 61440;

__device__ __forceinline__ unsigned short f2b(float v) {
    unsigned int u = __builtin_bit_cast(unsigned int, v);
    unsigned int r = (u + 0x7FFFu + ((u >> 16) & 1u)) >> 16;   // RNE
    return (unsigned short)r;
}
__device__ __forceinline__ float b2f(unsigned short h) {
    return __builtin_bit_cast(float, (unsigned int)h << 16);
}
__device__ __forceinline__ unsigned int cvtpk(float lo, float hi) {
    unsigned int r;
    asm("v_cvt_pk_bf16_f32 %0, %1, %2" : "=v"(r) : "v"(lo), "v"(hi));
    return r;   // low16 = bf16(lo), high16 = bf16(hi)
}
__device__ __forceinline__ void cvt2(float v0, float v1,
                                     unsigned int& hp, unsigned int& lp) {
    hp = cvtpk(v0, v1);
    float r0 = v0 - __builtin_bit_cast(float, hp << 16);
    float r1 = v1 - __builtin_bit_cast(float, hp & 0xFFFF0000u);
    lp = cvtpk(r0, r1);
}
__device__ __forceinline__ s16x8 asfrag(u32x4 u) {
    return __builtin_bit_cast(s16x8, u);
}
__device__ __forceinline__ f32x4 mm(s16x8 a, s16x8 b, f32x4 c) {
    return __builtin_amdgcn_mfma_f32_16x16x32_bf16(a, b, c, 0, 0, 0);
}
__device__ __forceinline__ float ftanh(float z) {
    float e = __expf(2.0f * z);
    float r = __builtin_amdgcn_rcpf(e + 1.0f);
    return fmaf(-2.0f, r, 1.0f);
}

__global__ __launch_bounds__(256) void pinn_prep(
    const float* __restrict__ alpha, const float* __restrict__ beta,
    const float* __restrict__ dtp,
    const float* __restrict__ W2, const float* __restrict__ W3,
    const float* __restrict__ W4, const float* __restrict__ W5,
    const float* __restrict__ Wout, unsigned short* __restrict__ wsu)
{
    int i = blockIdx.x * 256 + threadIdx.x;
    float v; int hi_off, lo_off;
    if (i < 16384) {                                   // hidden W^T A-frags
        int l = i >> 12, r = i & 4095;
        int t = r >> 9, jrt = t >> 1, krt = t & 1;
        int lane = (r >> 3) & 63, e = r & 7;
        int gg = lane >> 4;
        int j = 16 * jrt + (lane & 15);
        int n = 32 * krt + 16 * (e >> 2) + 4 * gg + (e & 3);
        const float* W = (l == 0) ? W2 : (l == 1) ? W3 : (l == 2) ? W4 : W5;
        v = (n < 50 && j < 50) ? W[n * 50 + j] : 0.0f;
        hi_off = i; lo_off = i + WH_LO;
    } else if (i < 23552) {                            // Wout^T A-frags
        int r = i - 16384;
        int t = r >> 9, jrt = t >> 1, krt = t & 1;
        int lane = (r >> 3) & 63, e = r & 7;
        int gg = lane >> 4;
        int j = 16 * jrt + (lane & 15);
        int n = 32 * krt + 16 * (e >> 2) + 4 * gg + (e & 3);
        v = (n < 50 && j < 100) ? Wout[n * 100 + j] : 0.0f;
        hi_off = WO_HI + r; lo_off = WO_LO + r;
    } else if (i < 37888) {                            // Mdt^T A-frags
        int r = i - 23552;
        int t = r >> 9, jrt = t >> 2, kt = t & 3;
        int lane = (r >> 3) & 63, e = r & 7;
        int gg = lane >> 4;
        int j = 16 * jrt + (lane & 15);
        int k = 32 * kt + 16 * (e >> 2) + 4 * gg + (e & 3);
        v = (j < 100 && k < 100) ? dtp[0] * (beta[k] - alpha[j * 100 + k]) : 0.0f;
        hi_off = MD_HI + r; lo_off = MD_LO + r;
    } else return;
    unsigned short h = f2b(v);
    wsu[hi_off] = h;
    wsu[lo_off] = f2b(v - b2f(h));
}

// One hidden layer, precision-tiered, split accumulator chains (r12 exact).
__device__ __forceinline__ void hidden_layer(
    const unsigned short* __restrict__ wsu, int Lb,
    const float* __restrict__ bias, int ln, int gg,
    const u32x4 (&gh)[2][4], const u32x4 (&gl0)[2],
    u32x4 (&nh)[2][4], u32x4 (&nl0)[2])
{
#pragma unroll
    for (int kd = 0; kd < 2; ++kd) {
#pragma unroll
        for (int ct = 0; ct < 4; ++ct) nh[kd][ct] = (u32x4){0u, 0u, 0u, 0u};
        nl0[kd] = (u32x4){0u, 0u, 0u, 0u};
    }
#pragma unroll
    for (int jrt = 0; jrt < 4; ++jrt) {
        f32x4 accA[4];
        f32x4 accB0a = {0.f, 0.f, 0.f, 0.f}, accB0b = {0.f, 0.f, 0.f, 0.f};
        f32x4 accB1  = {0.f, 0.f, 0.f, 0.f};
#pragma unroll
        for (int ct = 0; ct < 4; ++ct) accA[ct] = (f32x4){0.f, 0.f, 0.f, 0.f};
#pragma unroll
        for (int krt = 0; krt < 2; ++krt) {
            s16x8 wh = *(const s16x8*)(wsu + Lb + (jrt * 2 + krt) * 512 + ln * 8);
            s16x8 wl = *(const s16x8*)(wsu + WH_LO + Lb + (jrt * 2 + krt) * 512 + ln * 8);
            s16x8 b0h = asfrag(gh[krt][0]);
            s16x8 b0l = asfrag(gl0[krt]);
            s16x8 b1h = asfrag(gh[krt][1]);
            accA[0] = mm(wh, b0h, accA[0]);                 // jet0: 3-term
            accB0a  = mm(wh, b0l, accB0a);
            accB0b  = mm(wl, b0h, accB0b);
            accA[1] = mm(wh, b1h, accA[1]);                 // jet1: 2-term
            accB1   = mm(wl, b1h, accB1);
            accA[2] = mm(wh, asfrag(gh[krt][2]), accA[2]);  // jet2: 1-term
            accA[3] = mm(wh, asfrag(gh[krt][3]), accA[3]);  // jet3: 1-term
        }
        float bv[4];
        if (jrt < 3) {
            float4 b4 = *(const float4*)(bias + 16 * jrt + 4 * gg);
            bv[0] = b4.x; bv[1] = b4.y; bv[2] = b4.z; bv[3] = b4.w;
        } else {
#pragma unroll
            for (int r = 0; r < 4; ++r) {
                int j = 48 + 4 * gg + r;
                bv[r] = (j < 50) ? bias[j] : 0.0f;
            }
        }
        float m[4][4];
#pragma unroll
        for (int r = 0; r < 4; ++r) {
            float z0 = (accA[0][r] + accB0a[r]) + (accB0b[r] + bv[r]);
            float z1 = accA[1][r] + accB1[r];
            float z2 = accA[2][r];
            float z3 = accA[3][r];
            float t  = ftanh(z0);
            float sd = fmaf(-t, t, 1.0f);
            float c2 = -2.0f * t * sd;
            float c3 = -2.0f * sd * fmaf(3.0f, sd, -2.0f);
            float z1sq = z1 * z1;
            m[0][r] = t;
            m[1][r] = sd * z1;
            m[2][r] = fmaf(c2, z1sq, sd * z2);
            m[3][r] = fmaf(c3, z1sq * z1, fmaf(3.0f * c2, z1 * z2, sd * z3));
        }
        const int kd = jrt >> 1, p = jrt & 1;
        {   // jet0: hi + lo
            unsigned int hp0, lp0, hp1, lp1;
            cvt2(m[0][0], m[0][1], hp0, lp0);
            cvt2(m[0][2], m[0][3], hp1, lp1);
            nh[kd][0][2 * p]     = hp0;
            nh[kd][0][2 * p + 1] = hp1;
            nl0[kd][2 * p]       = lp0;
            nl0[kd][2 * p + 1]   = lp1;
        }
#pragma unroll
        for (int ct = 1; ct < 4; ++ct) {                    // jets 1-3: hi only
            nh[kd][ct][2 * p]     = cvtpk(m[ct][0], m[ct][1]);
            nh[kd][ct][2 * p + 1] = cvtpk(m[ct][2], m[ct][3]);
        }
    }
}

__global__ __launch_bounds__(128, 4) void pinn_main(
    const float* __restrict__ X, int N,
    const float* __restrict__ W1, const float* __restrict__ b1,
    const float* __restrict__ b2, const float* __restrict__ b3,
    const float* __restrict__ b4, const float* __restrict__ b5,
    const float* __restrict__ bout,
    const float* __restrict__ l1p, const float* __restrict__ l2p,
    const unsigned short* __restrict__ wsu,
    float* __restrict__ out)
{
    const int tid = threadIdx.x;
    const int wv = tid >> 6, ln = tid & 63;
    const int cc = ln & 15, gg = ln >> 4;
    const int n0 = blockIdx.x * 32 + wv * 16;

    u32x4 gAh[2][4], gAl0[2], gBh[2][4], gBl0[2];
#pragma unroll
    for (int krt = 0; krt < 2; ++krt) {
#pragma unroll
        for (int ct = 0; ct < 4; ++ct) gAh[krt][ct] = (u32x4){0u, 0u, 0u, 0u};
        gAl0[krt] = (u32x4){0u, 0u, 0u, 0u};
    }

    // ---- layer 1: width 1 -> 50, jets (x,1,0,0), in-lane packing ----
    float x = (n0 + cc < N) ? X[n0 + cc] : 0.0f;
#pragma unroll
    for (int krt = 0; krt < 2; ++krt)
#pragma unroll
        for (int jf = 0; jf < 2; ++jf) {
            float m[4][4];
#pragma unroll
            for (int q = 0; q < 4; ++q) {
                int n = 32 * krt + 16 * jf + 4 * gg + q;
                float w = (n < 50) ? W1[n] : 0.0f;
                float b = (n < 50) ? b1[n] : 0.0f;
                float z0 = fmaf(x, w, b);
                float t  = ftanh(z0);
                float sd = fmaf(-t, t, 1.0f);
                float c2 = -2.0f * t * sd;
                float c3 = -2.0f * sd * fmaf(3.0f, sd, -2.0f);
                float w2 = w * w;
                m[0][q] = t; m[1][q] = sd * w; m[2][q] = c2 * w2; m[3][q] = c3 * w2 * w;
            }
            {
                unsigned int hp0, lp0, hp1, lp1;
                cvt2(m[0][0], m[0][1], hp0, lp0);
                cvt2(m[0][2], m[0][3], hp1, lp1);
                gAh[krt][0][2 * jf]     = hp0;
                gAh[krt][0][2 * jf + 1] = hp1;
                gAl0[krt][2 * jf]       = lp0;
                gAl0[krt][2 * jf + 1]   = lp1;
            }
#pragma unroll
            for (int ct = 1; ct < 4; ++ct) {
                gAh[krt][ct][2 * jf]     = cvtpk(m[ct][0], m[ct][1]);
                gAh[krt][ct][2 * jf + 1] = cvtpk(m[ct][2], m[ct][3]);
            }
        }

    // ---- layers 2..5 (A->B->A->B->A) ----
#pragma unroll 1
    for (int L = 0; L < 2; ++L) {
        hidden_layer(wsu, (2 * L) * 4096,     (L == 0) ? b2 : b4, ln, gg,
                     gAh, gAl0, gBh, gBl0);
        hidden_layer(wsu, (2 * L + 1) * 4096, (L == 0) ? b3 : b5, ln, gg,
                     gBh, gBl0, gAh, gAl0);
    }

    // ---- head: a0 3-term (split chains), a1 2-term, a3 1-term; u0 in regs ----
    const float l1v = l1p[0], l2v = l2p[0];
    float u0s[7][4];
    u32x4 fhU[4];
#pragma unroll
    for (int kt = 0; kt < 4; ++kt) fhU[kt] = (u32x4){0u, 0u, 0u, 0u};
#pragma unroll
    for (int jrt = 0; jrt < 7; ++jrt) {
        f32x4 a0A = {0.f, 0.f, 0.f, 0.f}, a0B = {0.f, 0.f, 0.f, 0.f};
        f32x4 a0C = {0.f, 0.f, 0.f, 0.f};
        f32x4 a1A = {0.f, 0.f, 0.f, 0.f}, a1B = {0.f, 0.f, 0.f, 0.f};
        f32x4 a3A = {0.f, 0.f, 0.f, 0.f};
#pragma unroll
        for (int krt = 0; krt < 2; ++krt) {
            s16x8 wh = *(const s16x8*)(wsu + WO_HI + (jrt * 2 + krt) * 512 + ln * 8);
            s16x8 wl = *(const s16x8*)(wsu + WO_LO + (jrt * 2 + krt) * 512 + ln * 8);
            s16x8 b0h = asfrag(gAh[krt][0]);
            s16x8 b0l = asfrag(gAl0[krt]);
            s16x8 b1h = asfrag(gAh[krt][1]);
            a0A = mm(wh, b0h, a0A);
            a0B = mm(wh, b0l, a0B);
            a0C = mm(wl, b0h, a0C);
            a1A = mm(wh, b1h, a1A);
            a1B = mm(wl, b1h, a1B);
            a3A = mm(wh, asfrag(gAh[krt][3]), a3A);
        }
        float bo[4];
        if (jrt < 6) {
            float4 b4 = *(const float4*)(bout + 16 * jrt + 4 * gg);
            bo[0] = b4.x; bo[1] = b4.y; bo[2] = b4.z; bo[3] = b4.w;
        } else {
#pragma unroll
            for (int r = 0; r < 4; ++r) {
                int j = 96 + 4 * gg + r;
                bo[r] = (j < 100) ? bout[j] : 0.0f;
            }
        }
        float fv[4];
#pragma unroll
        for (int r = 0; r < 4; ++r) {
            float u0 = (a0A[r] + a0B[r]) + (a0C[r] + bo[r]);
            u0s[jrt][r] = u0;
            fv[r] = -(l1v * u0) * (a1A[r] + a1B[r]) - l2v * a3A[r];
        }
        const int kt = jrt >> 1, p = jrt & 1;
        fhU[kt][2 * p]     = cvtpk(fv[0], fv[1]);
        fhU[kt][2 * p + 1] = cvtpk(fv[2], fv[3]);
    }

    // ---- final: out = u0 + Mdt^T @ F^T; direct float4 store per jrt ----
    const bool act = (n0 + cc) < N;
    float* orow = out + (size_t)(n0 + cc) * 100;
#pragma unroll
    for (int jrt = 0; jrt < 7; ++jrt) {
        f32x4 accA = {0.f, 0.f, 0.f, 0.f}, accB = {0.f, 0.f, 0.f, 0.f};
        f32x4 accC = {0.f, 0.f, 0.f, 0.f}, accD = {0.f, 0.f, 0.f, 0.f};
#pragma unroll
        for (int kt = 0; kt < 4; ++kt) {
            s16x8 mh = *(const s16x8*)(wsu + MD_HI + (jrt * 4 + kt) * 512 + ln * 8);
            s16x8 ml = *(const s16x8*)(wsu + MD_LO + (jrt * 4 + kt) * 512 + ln * 8);
            s16x8 fb = asfrag(fhU[kt]);
            if (kt & 1) { accC = mm(mh, fb, accC); accD = mm(ml, fb, accD); }
            else        { accA = mm(mh, fb, accA); accB = mm(ml, fb, accB); }
        }
        if (act && (jrt < 6 || gg == 0)) {
            float4 v = make_float4(
                u0s[jrt][0] + (accA[0] + accB[0]) + (accC[0] + accD[0]),
                u0s[jrt][1] + (accA[1] + accB[1]) + (accC[1] + accD[1]),
                u0s[jrt][2] + (accA[2] + accB[2]) + (accC[2] + accD[2]),
                u0s[jrt][3] + (accA[3] + accB[3]) + (accC[3] + accD[3]));
            *(float4*)(orow + 16 * jrt + 4 * gg) = v;
        }
    }
}

extern "C" void kernel_launch(void* const* d_in, const int* in_sizes, int n_in,
                              void* d_out, int out_size, void* d_ws, size_t ws_size,
                              hipStream_t stream)
{
    const float* X     = (const float*)d_in[0];
    const float* dt    = (const float*)d_in[1];
    const float* alpha = (const float*)d_in[2];
    const float* beta  = (const float*)d_in[3];
    const float* W1    = (const float*)d_in[4];
    const float* b1    = (const float*)d_in[5];
    const float* W2    = (const float*)d_in[6];
    const float* b2    = (const float*)d_in[7];
    const float* W3    = (const float*)d_in[8];
    const float* b3    = (const float*)d_in[9];
    const float* W4    = (const float*)d_in[10];
    const float* b4    = (const float*)d_in[11];
    const float* W5    = (const float*)d_in[12];
    const float* b5    = (const float*)d_in[13];
    const float* Wout  = (const float*)d_in[14];
    const float* bout  = (const float*)d_in[15];
    const float* l1    = (const float*)d_in[16];
    const float* l2    = (const float*)d_in[17];

    unsigned short* wsu = (unsigned short*)d_ws;
    int N = in_sizes[0];

    pinn_prep<<<148, 256, 0, stream>>>(alpha, beta, dt, W2, W3, W4, W5, Wout, wsu);

    int grid = (N + 31) / 32;
    pinn_main<<<grid, 128, 0, stream>>>(X, N, W1, b1, b2, b3, b4, b5,
                                        bout, l1, l2, wsu, (float*)d_out);
}